// Round 2
// baseline (1349.397 us; speedup 1.0000x reference)
//
#include <hip/hip_runtime.h>

// B=2, T=2048, D=1024, H=16, HD=64.
// Inputs f32 (x, rope, W_attn, W_proj), mask ignored (causal recomputed).
// Output f32. Internal tensors (qkv, Q, K, V, O) bf16 in workspace.

typedef __bf16 bf16x8 __attribute__((ext_vector_type(8)));
typedef float f32x4 __attribute__((ext_vector_type(4)));

__device__ __forceinline__ float bf2f(unsigned short u) {
  unsigned int i = ((unsigned int)u) << 16;
  return __builtin_bit_cast(float, i);
}
__device__ __forceinline__ unsigned short f2bf(float f) {
  unsigned int i = __builtin_bit_cast(unsigned int, f);
  i += 0x7FFFu + ((i >> 16) & 1u);   // round-to-nearest-even
  return (unsigned short)(i >> 16);
}

// ---------------------------------------------------------------------------
// GEMM: C(MxN) = A(MxK) * B(KxN). A: f32 or bf16 (template), B: f32,
// C: f32 or bf16 (template). bf16 MFMA, f32 accumulate.
// 64x64 tile, BK=32, 4 waves, each 32x32 via 2x2 mfma_f32_16x16x32_bf16.
// ---------------------------------------------------------------------------
template<bool A_IS_F32, bool C_IS_F32>
__global__ __launch_bounds__(256) void gemm_kernel(
    const void* __restrict__ Ap, const float* __restrict__ Bp,
    void* __restrict__ Cp, int M, int N, int K)
{
  __shared__ unsigned short As[64][40];   // [m][k] padded
  __shared__ unsigned short BsT[64][40];  // [n][k] padded

  const int tid = threadIdx.x;
  const int m0 = blockIdx.y * 64, n0 = blockIdx.x * 64;
  const int w = tid >> 6, lane = tid & 63;
  const int wr = (w >> 1) * 32, wc = (w & 1) * 32;
  const int q = lane >> 4, r = lane & 15;

  f32x4 acc[2][2];
#pragma unroll
  for (int i = 0; i < 2; ++i)
#pragma unroll
    for (int j = 0; j < 2; ++j)
      acc[i][j] = f32x4{0.f, 0.f, 0.f, 0.f};

  const int arow = tid >> 2, ak = (tid & 3) << 3;  // 64 rows x 32 k, 8 elems/thread
  const int bk = tid >> 3, bn = (tid & 7) << 3;    // 32 k x 64 n, 8 elems/thread

  for (int k0 = 0; k0 < K; k0 += 32) {
    __syncthreads();
    if constexpr (A_IS_F32) {
      const float* A = (const float*)Ap;
      const float* ap = &A[(size_t)(m0 + arow) * K + k0 + ak];
      float4 a0 = *reinterpret_cast<const float4*>(ap);
      float4 a1 = *reinterpret_cast<const float4*>(ap + 4);
      uint4 pk;
      pk.x = (unsigned int)f2bf(a0.x) | ((unsigned int)f2bf(a0.y) << 16);
      pk.y = (unsigned int)f2bf(a0.z) | ((unsigned int)f2bf(a0.w) << 16);
      pk.z = (unsigned int)f2bf(a1.x) | ((unsigned int)f2bf(a1.y) << 16);
      pk.w = (unsigned int)f2bf(a1.z) | ((unsigned int)f2bf(a1.w) << 16);
      *reinterpret_cast<uint4*>(&As[arow][ak]) = pk;
    } else {
      const unsigned short* A = (const unsigned short*)Ap;
      uint4 av = *reinterpret_cast<const uint4*>(&A[(size_t)(m0 + arow) * K + k0 + ak]);
      *reinterpret_cast<uint4*>(&As[arow][ak]) = av;
    }
    {
      const float* bp = &Bp[(size_t)(k0 + bk) * N + n0 + bn];
      float4 b0 = *reinterpret_cast<const float4*>(bp);
      float4 b1 = *reinterpret_cast<const float4*>(bp + 4);
      float bw[8] = {b0.x, b0.y, b0.z, b0.w, b1.x, b1.y, b1.z, b1.w};
#pragma unroll
      for (int i = 0; i < 8; ++i) BsT[bn + i][bk] = f2bf(bw[i]);
    }
    __syncthreads();

    bf16x8 af[2], bfr[2];
#pragma unroll
    for (int i = 0; i < 2; ++i)
      af[i] = __builtin_bit_cast(bf16x8,
          *reinterpret_cast<const uint4*>(&As[wr + i * 16 + r][q * 8]));
#pragma unroll
    for (int j = 0; j < 2; ++j)
      bfr[j] = __builtin_bit_cast(bf16x8,
          *reinterpret_cast<const uint4*>(&BsT[wc + j * 16 + r][q * 8]));
#pragma unroll
    for (int i = 0; i < 2; ++i)
#pragma unroll
      for (int j = 0; j < 2; ++j)
        acc[i][j] = __builtin_amdgcn_mfma_f32_16x16x32_bf16(af[i], bfr[j], acc[i][j], 0, 0, 0);
  }

  // D layout: col = lane&15, row = (lane>>4)*4 + reg
#pragma unroll
  for (int i = 0; i < 2; ++i)
#pragma unroll
    for (int j = 0; j < 2; ++j)
#pragma unroll
      for (int reg = 0; reg < 4; ++reg) {
        int row = m0 + wr + i * 16 + q * 4 + reg;
        int col = n0 + wc + j * 16 + r;
        if constexpr (C_IS_F32)
          ((float*)Cp)[(size_t)row * N + col] = acc[i][j][reg];
        else
          ((unsigned short*)Cp)[(size_t)row * N + col] = f2bf(acc[i][j][reg]);
      }
}

// ---------------------------------------------------------------------------
// RoPE + scatter: qkv bf16 (B,T,3D) -> Q,K (rope'd), V in (B,H,T,HD) bf16.
// rope is f32 (T, HD/2, 2). 4 elements (2 rope pairs) per thread.
// ---------------------------------------------------------------------------
__global__ __launch_bounds__(256) void rope_scatter_kernel(
    const unsigned short* __restrict__ qkv, const float* __restrict__ rope,
    unsigned short* __restrict__ Qb, unsigned short* __restrict__ Kb,
    unsigned short* __restrict__ Vb)
{
  int gid = blockIdx.x * 256 + threadIdx.x;   // 0 .. B*T*3D/4 - 1
  int rowM = gid / 768;
  int c4 = (gid - rowM * 768) * 4;
  int b = rowM >> 11, t = rowM & 2047;
  int sec = c4 >> 10;                         // 0=q 1=k 2=v
  int d = c4 & 1023;
  int h = d >> 6, hd = d & 63;

  uint2 vv = *reinterpret_cast<const uint2*>(&qkv[(size_t)rowM * 3072 + c4]);
  size_t dst = ((size_t)(b * 16 + h) * 2048 + t) * 64 + hd;

  if (sec == 2) {
    *reinterpret_cast<uint2*>(&Vb[dst]) = vv;
    return;
  }
  float x0 = bf2f((unsigned short)(vv.x & 0xffffu));
  float x1 = bf2f((unsigned short)(vv.x >> 16));
  float x2 = bf2f((unsigned short)(vv.y & 0xffffu));
  float x3 = bf2f((unsigned short)(vv.y >> 16));
  float4 rc = *reinterpret_cast<const float4*>(&rope[(size_t)t * 64 + hd]);
  float y0 = x0 * rc.x - x1 * rc.y;
  float y1 = x1 * rc.x + x0 * rc.y;
  float y2 = x2 * rc.z - x3 * rc.w;
  float y3 = x3 * rc.z + x2 * rc.w;
  uint2 outv;
  outv.x = (unsigned int)f2bf(y0) | ((unsigned int)f2bf(y1) << 16);
  outv.y = (unsigned int)f2bf(y2) | ((unsigned int)f2bf(y3) << 16);
  unsigned short* dstp = (sec == 0) ? Qb : Kb;
  *reinterpret_cast<uint2*>(&dstp[dst]) = outv;
}

// ---------------------------------------------------------------------------
// Causal flash attention (vector version). Q/K/V bf16 (B,H,T,64).
// 512 threads = 8 waves; wave w owns q-rows r0..r0+3 (32 rows/block).
// Online softmax; O written bf16 in (B,T,D) layout.
// ---------------------------------------------------------------------------
__global__ __launch_bounds__(512) void attn_kernel(
    const unsigned short* __restrict__ Q, const unsigned short* __restrict__ K,
    const unsigned short* __restrict__ V, unsigned short* __restrict__ O)
{
  __shared__ float Kt[64][68];      // [d][key], padded
  __shared__ float Vt[64][64];      // [key][d]
  __shared__ float q4[8][64][4];    // [wave][d][row]
  __shared__ float p4s[8][64][4];   // [wave][key][row]

  const int bh = blockIdx.x >> 6;
  const int tile = blockIdx.x & 63;
  const int b = bh >> 4, h = bh & 15;
  const size_t base = (size_t)bh * 2048 * 64;
  const unsigned short* Qb = Q + base;
  const unsigned short* Kb = K + base;
  const unsigned short* Vb = V + base;

  const int tid = threadIdx.x, w = tid >> 6, lane = tid & 63;
  const int r0 = tile * 32 + w * 4;

#pragma unroll
  for (int rr = 0; rr < 4; ++rr)
    q4[w][lane][rr] = bf2f(Qb[(size_t)(r0 + rr) * 64 + lane]);

  float m[4], l[4], o[4];
#pragma unroll
  for (int rr = 0; rr < 4; ++rr) { m[rr] = -1e30f; l[rr] = 0.f; o[rr] = 0.f; }

  const int nch = (tile * 32 + 31) / 64 + 1;
  const int kk = tid >> 3, dc = (tid & 7) << 3;

  for (int c = 0; c < nch; ++c) {
    __syncthreads();
    const size_t krow = (size_t)(c * 64 + kk) * 64 + dc;
    uint4 kv16 = *reinterpret_cast<const uint4*>(&Kb[krow]);
    unsigned int ka[4] = {kv16.x, kv16.y, kv16.z, kv16.w};
#pragma unroll
    for (int i = 0; i < 4; ++i) {
      Kt[dc + 2 * i][kk]     = bf2f((unsigned short)(ka[i] & 0xffffu));
      Kt[dc + 2 * i + 1][kk] = bf2f((unsigned short)(ka[i] >> 16));
    }
    uint4 vv16 = *reinterpret_cast<const uint4*>(&Vb[krow]);
    unsigned int va[4] = {vv16.x, vv16.y, vv16.z, vv16.w};
    float4 vlo = make_float4(bf2f((unsigned short)(va[0] & 0xffffu)),
                             bf2f((unsigned short)(va[0] >> 16)),
                             bf2f((unsigned short)(va[1] & 0xffffu)),
                             bf2f((unsigned short)(va[1] >> 16)));
    float4 vhi = make_float4(bf2f((unsigned short)(va[2] & 0xffffu)),
                             bf2f((unsigned short)(va[2] >> 16)),
                             bf2f((unsigned short)(va[3] & 0xffffu)),
                             bf2f((unsigned short)(va[3] >> 16)));
    *reinterpret_cast<float4*>(&Vt[kk][dc])     = vlo;
    *reinterpret_cast<float4*>(&Vt[kk][dc + 4]) = vhi;
    __syncthreads();

    float s0 = 0.f, s1 = 0.f, s2 = 0.f, s3 = 0.f;
#pragma unroll 16
    for (int d = 0; d < 64; ++d) {
      float kvv = Kt[d][lane];
      float4 qv = *reinterpret_cast<const float4*>(&q4[w][d][0]);
      s0 += qv.x * kvv; s1 += qv.y * kvv; s2 += qv.z * kvv; s3 += qv.w * kvv;
    }
    float s[4] = {s0, s1, s2, s3};
    const int key = c * 64 + lane;
    float p[4];
#pragma unroll
    for (int rr = 0; rr < 4; ++rr) {
      float sv = s[rr] * 0.125f;
      if (key > r0 + rr) sv = -1e30f;
      float red = sv;
#pragma unroll
      for (int off = 32; off; off >>= 1)
        red = fmaxf(red, __shfl_xor(red, off));
      float mn = fmaxf(m[rr], red);
      float alpha = __expf(m[rr] - mn);
      m[rr] = mn;
      p[rr] = __expf(sv - mn);
      l[rr] = l[rr] * alpha + p[rr];
      o[rr] *= alpha;
    }
    *reinterpret_cast<float4*>(&p4s[w][lane][0]) = make_float4(p[0], p[1], p[2], p[3]);

#pragma unroll 16
    for (int jj = 0; jj < 64; ++jj) {
      float4 pv = *reinterpret_cast<const float4*>(&p4s[w][jj][0]);
      float vvv = Vt[jj][lane];
      o[0] += pv.x * vvv; o[1] += pv.y * vvv; o[2] += pv.z * vvv; o[3] += pv.w * vvv;
    }
  }

#pragma unroll
  for (int rr = 0; rr < 4; ++rr) {
    float sum = l[rr];
#pragma unroll
    for (int off = 32; off; off >>= 1) sum += __shfl_xor(sum, off);
    float res = o[rr] / sum;
    size_t oi = ((size_t)(b * 2048 + (r0 + rr)) * 16 + h) * 64 + lane;
    O[oi] = f2bf(res);
  }
}

// ---------------------------------------------------------------------------
extern "C" void kernel_launch(void* const* d_in, const int* in_sizes, int n_in,
                              void* d_out, int out_size, void* d_ws, size_t ws_size,
                              hipStream_t stream)
{
  (void)in_sizes; (void)n_in; (void)out_size; (void)ws_size;
  const float* x    = (const float*)d_in[0];   // (B,T,D) f32
  const float* rope = (const float*)d_in[1];   // (T,32,2) f32
  const float* Wa   = (const float*)d_in[2];   // (D,3D) f32
  const float* Wp   = (const float*)d_in[3];   // (D,D) f32
  // d_in[4] = causal mask (ignored; recomputed)

  unsigned short* qkv = (unsigned short*)d_ws;             // 4096x3072 bf16
  unsigned short* Qb  = qkv + (size_t)4096 * 3072;         // (B,H,T,64) bf16
  unsigned short* Kb  = Qb + (size_t)32 * 2048 * 64;
  unsigned short* Vb  = Kb + (size_t)32 * 2048 * 64;
  unsigned short* O   = qkv;  // qkv region dead after rope kernel -> reuse
  float* out = (float*)d_out;

  gemm_kernel<true, false><<<dim3(3072 / 64, 4096 / 64), 256, 0, stream>>>(
      x, Wa, qkv, 4096, 3072, 1024);
  rope_scatter_kernel<<<(4096 * 3072 / 4) / 256, 256, 0, stream>>>(qkv, rope, Qb, Kb, Vb);
  attn_kernel<<<32 * 64, 512, 0, stream>>>(Qb, Kb, Vb, O);
  gemm_kernel<false, true><<<dim3(1024 / 64, 4096 / 64), 256, 0, stream>>>(
      O, Wp, out, 4096, 1024, 1024);
}

// Round 4
// 410.560 us; speedup vs baseline: 3.2867x; 3.2867x over previous
//
#include <hip/hip_runtime.h>

// B=2, T=2048, D=1024, H=16, HD=64.
// Inputs f32 (x, rope, W_attn, W_proj), mask ignored (causal recomputed).
// Output f32. Internal tensors (qkv, Q, K, V, O) bf16 in workspace.

typedef __bf16 bf16x8 __attribute__((ext_vector_type(8)));
typedef float f32x4 __attribute__((ext_vector_type(4)));

__device__ __forceinline__ float bf2f(unsigned short u) {
  unsigned int i = ((unsigned int)u) << 16;
  return __builtin_bit_cast(float, i);
}
__device__ __forceinline__ unsigned short f2bf(float f) {
  unsigned int i = __builtin_bit_cast(unsigned int, f);
  i += 0x7FFFu + ((i >> 16) & 1u);   // round-to-nearest-even
  return (unsigned short)(i >> 16);
}

// ---------------------------------------------------------------------------
// GEMM: C(MxN) = A(MxK) * B(KxN). A: f32 or bf16 (template), B: f32,
// C: f32 or bf16 (template). bf16 MFMA, f32 accumulate.
// 64x64 tile, BK=32, 4 waves, each 32x32 via 2x2 mfma_f32_16x16x32_bf16.
// ---------------------------------------------------------------------------
template<bool A_IS_F32, bool C_IS_F32>
__global__ __launch_bounds__(256) void gemm_kernel(
    const void* __restrict__ Ap, const float* __restrict__ Bp,
    void* __restrict__ Cp, int M, int N, int K)
{
  __shared__ unsigned short As[64][40];   // [m][k] padded
  __shared__ unsigned short BsT[64][40];  // [n][k] padded

  const int tid = threadIdx.x;
  const int m0 = blockIdx.y * 64, n0 = blockIdx.x * 64;
  const int w = tid >> 6, lane = tid & 63;
  const int wr = (w >> 1) * 32, wc = (w & 1) * 32;
  const int q = lane >> 4, r = lane & 15;

  f32x4 acc[2][2];
#pragma unroll
  for (int i = 0; i < 2; ++i)
#pragma unroll
    for (int j = 0; j < 2; ++j)
      acc[i][j] = f32x4{0.f, 0.f, 0.f, 0.f};

  const int arow = tid >> 2, ak = (tid & 3) << 3;  // 64 rows x 32 k
  const int bk = tid >> 3, bn = (tid & 7) << 3;    // 32 k x 64 n

  for (int k0 = 0; k0 < K; k0 += 32) {
    __syncthreads();
    if constexpr (A_IS_F32) {
      const float* A = (const float*)Ap;
      const float* ap = &A[(size_t)(m0 + arow) * K + k0 + ak];
      float4 a0 = *reinterpret_cast<const float4*>(ap);
      float4 a1 = *reinterpret_cast<const float4*>(ap + 4);
      uint4 pk;
      pk.x = (unsigned int)f2bf(a0.x) | ((unsigned int)f2bf(a0.y) << 16);
      pk.y = (unsigned int)f2bf(a0.z) | ((unsigned int)f2bf(a0.w) << 16);
      pk.z = (unsigned int)f2bf(a1.x) | ((unsigned int)f2bf(a1.y) << 16);
      pk.w = (unsigned int)f2bf(a1.z) | ((unsigned int)f2bf(a1.w) << 16);
      *reinterpret_cast<uint4*>(&As[arow][ak]) = pk;
    } else {
      const unsigned short* A = (const unsigned short*)Ap;
      uint4 av = *reinterpret_cast<const uint4*>(&A[(size_t)(m0 + arow) * K + k0 + ak]);
      *reinterpret_cast<uint4*>(&As[arow][ak]) = av;
    }
    {
      const float* bp = &Bp[(size_t)(k0 + bk) * N + n0 + bn];
      float4 b0 = *reinterpret_cast<const float4*>(bp);
      float4 b1 = *reinterpret_cast<const float4*>(bp + 4);
      float bw[8] = {b0.x, b0.y, b0.z, b0.w, b1.x, b1.y, b1.z, b1.w};
#pragma unroll
      for (int i = 0; i < 8; ++i) BsT[bn + i][bk] = f2bf(bw[i]);
    }
    __syncthreads();

    bf16x8 af[2], bfr[2];
#pragma unroll
    for (int i = 0; i < 2; ++i)
      af[i] = __builtin_bit_cast(bf16x8,
          *reinterpret_cast<const uint4*>(&As[wr + i * 16 + r][q * 8]));
#pragma unroll
    for (int j = 0; j < 2; ++j)
      bfr[j] = __builtin_bit_cast(bf16x8,
          *reinterpret_cast<const uint4*>(&BsT[wc + j * 16 + r][q * 8]));
#pragma unroll
    for (int i = 0; i < 2; ++i)
#pragma unroll
      for (int j = 0; j < 2; ++j)
        acc[i][j] = __builtin_amdgcn_mfma_f32_16x16x32_bf16(af[i], bfr[j], acc[i][j], 0, 0, 0);
  }

  // D layout: col = lane&15, row = (lane>>4)*4 + reg
#pragma unroll
  for (int i = 0; i < 2; ++i)
#pragma unroll
    for (int j = 0; j < 2; ++j)
#pragma unroll
      for (int reg = 0; reg < 4; ++reg) {
        int row = m0 + wr + i * 16 + q * 4 + reg;
        int col = n0 + wc + j * 16 + r;
        if constexpr (C_IS_F32)
          ((float*)Cp)[(size_t)row * N + col] = acc[i][j][reg];
        else
          ((unsigned short*)Cp)[(size_t)row * N + col] = f2bf(acc[i][j][reg]);
      }
}

// ---------------------------------------------------------------------------
// RoPE + scatter: qkv bf16 (B,T,3D) -> Q,K (rope'd), V in (B,H,T,HD) bf16.
// ---------------------------------------------------------------------------
__global__ __launch_bounds__(256) void rope_scatter_kernel(
    const unsigned short* __restrict__ qkv, const float* __restrict__ rope,
    unsigned short* __restrict__ Qb, unsigned short* __restrict__ Kb,
    unsigned short* __restrict__ Vb)
{
  int gid = blockIdx.x * 256 + threadIdx.x;
  int rowM = gid / 768;
  int c4 = (gid - rowM * 768) * 4;
  int b = rowM >> 11, t = rowM & 2047;
  int sec = c4 >> 10;                         // 0=q 1=k 2=v
  int d = c4 & 1023;
  int h = d >> 6, hd = d & 63;

  uint2 vv = *reinterpret_cast<const uint2*>(&qkv[(size_t)rowM * 3072 + c4]);
  size_t dst = ((size_t)(b * 16 + h) * 2048 + t) * 64 + hd;

  if (sec == 2) {
    *reinterpret_cast<uint2*>(&Vb[dst]) = vv;
    return;
  }
  float x0 = bf2f((unsigned short)(vv.x & 0xffffu));
  float x1 = bf2f((unsigned short)(vv.x >> 16));
  float x2 = bf2f((unsigned short)(vv.y & 0xffffu));
  float x3 = bf2f((unsigned short)(vv.y >> 16));
  float4 rc = *reinterpret_cast<const float4*>(&rope[(size_t)t * 64 + hd]);
  float y0 = x0 * rc.x - x1 * rc.y;
  float y1 = x1 * rc.x + x0 * rc.y;
  float y2 = x2 * rc.z - x3 * rc.w;
  float y3 = x3 * rc.z + x2 * rc.w;
  uint2 outv;
  outv.x = (unsigned int)f2bf(y0) | ((unsigned int)f2bf(y1) << 16);
  outv.y = (unsigned int)f2bf(y2) | ((unsigned int)f2bf(y3) << 16);
  unsigned short* dstp = (sec == 0) ? Qb : Kb;
  *reinterpret_cast<uint2*>(&dstp[dst]) = outv;
}

// ---------------------------------------------------------------------------
// MFMA causal flash attention. Q/K/V bf16 (B,H,T,64); O bf16 (B,T,D).
// 256 threads = 4 waves. Q-tile 128 rows (32/wave). K-tile 64 keys.
// All LDS tiles [64][64] bf16 with T2 XOR swizzle: byte ^= (row&7)<<4.
// Online softmax in registers (16-lane-group shuffle reduce), base-2 exp
// with scale folded: softmax(S/8) == exp2((S - rowmax) * 0.125*log2(e)).
// ---------------------------------------------------------------------------
__global__ __launch_bounds__(256) void attn_mfma_kernel(
    const unsigned short* __restrict__ Q, const unsigned short* __restrict__ K,
    const unsigned short* __restrict__ V, unsigned short* __restrict__ O)
{
  __shared__ unsigned short Ks[64 * 64];     // [key][d] swizzled
  __shared__ unsigned short Vt[64 * 64];     // [d][key] swizzled (transposed)
  __shared__ unsigned short Ps[4][32 * 64];  // per-wave P [row][key] swizzled

  const int bx = blockIdx.x;
  const int idx = bx & 255, hi = bx >> 8;
  const int bh = hi * 16 + (idx >> 4);
  const int tp = idx & 15;
  const int tile = hi ? tp : 15 - tp;        // complementary work pairing
  const int b = bh >> 4, h = bh & 15;
  const size_t base = (size_t)bh * 2048 * 64;

  const int tid = threadIdx.x, w = tid >> 6, lane = tid & 63;
  const int g = lane >> 4, r = lane & 15;
  const int q0 = tile * 128;
  const int wrow0 = q0 + w * 32;             // wave's first q-row

  // Q fragments [i][kk]: A-operand, row = wrow0+i*16+r, d = kk*32+g*8
  bf16x8 qf[2][2];
#pragma unroll
  for (int i = 0; i < 2; ++i)
#pragma unroll
    for (int kk = 0; kk < 2; ++kk)
      qf[i][kk] = __builtin_bit_cast(bf16x8, *reinterpret_cast<const uint4*>(
          &Q[base + (size_t)(wrow0 + i * 16 + r) * 64 + kk * 32 + g * 8]));

  float m[2][4], l[2][4];
  f32x4 ov[2][4];
#pragma unroll
  for (int i = 0; i < 2; ++i) {
#pragma unroll
    for (int reg = 0; reg < 4; ++reg) { m[i][reg] = -1e30f; l[i][reg] = 0.f; }
#pragma unroll
    for (int df = 0; df < 4; ++df) ov[i][df] = f32x4{0.f, 0.f, 0.f, 0.f};
  }

  unsigned short* Pw = &Ps[w][0];
  const float cs = 0.125f * 1.44269504f;
  const int nkt = (q0 >> 6) + 2;

  for (int c = 0; c < nkt; ++c) {
    const int kb = c * 64;
    __syncthreads();   // previous tile fully consumed
    // --- stage K: coalesced row loads, swizzled LDS writes ---
    {
      const int c8 = (tid & 7) * 8;
      int row = tid >> 3;
#pragma unroll
      for (int it = 0; it < 2; ++it, row += 32) {
        uint4 kv = *reinterpret_cast<const uint4*>(&K[base + (size_t)(kb + row) * 64 + c8]);
        char* p = (char*)Ks + row * 128 + ((c8 * 2) ^ ((row & 7) << 4));
        *reinterpret_cast<uint4*>(p) = kv;
      }
    }
    // --- stage V transposed: lane=d (coalesced 128B/instr), pack 16 keys ---
    {
      const int d = tid & 63, kb16 = (tid >> 6) * 16;
      unsigned int pk[8];
#pragma unroll
      for (int j = 0; j < 8; ++j) {
        unsigned int lo  = V[base + (size_t)(kb + kb16 + 2 * j) * 64 + d];
        unsigned int hiu = V[base + (size_t)(kb + kb16 + 2 * j + 1) * 64 + d];
        pk[j] = lo | (hiu << 16);
      }
      char* pr = (char*)Vt + d * 128;
      int cA = (kb16 * 2) ^ ((d & 7) << 4);
      int cB = (kb16 * 2 + 16) ^ ((d & 7) << 4);
      *reinterpret_cast<uint4*>(pr + cA) = uint4{pk[0], pk[1], pk[2], pk[3]};
      *reinterpret_cast<uint4*>(pr + cB) = uint4{pk[4], pk[5], pk[6], pk[7]};
    }
    __syncthreads();

    if (kb > wrow0 + 31) continue;   // fully masked for this wave (barriers done)

    // --- QK^T: S = Q * K^T ---
    f32x4 s[2][4];
#pragma unroll
    for (int i = 0; i < 2; ++i)
#pragma unroll
      for (int cf = 0; cf < 4; ++cf) s[i][cf] = f32x4{0.f, 0.f, 0.f, 0.f};
#pragma unroll
    for (int kk = 0; kk < 2; ++kk) {
      bf16x8 kf[4];
#pragma unroll
      for (int cf = 0; cf < 4; ++cf) {
        int row = cf * 16 + r;
        const char* p = (const char*)Ks + row * 128 + ((kk * 64 + g * 16) ^ ((r & 7) << 4));
        kf[cf] = __builtin_bit_cast(bf16x8, *reinterpret_cast<const uint4*>(p));
      }
#pragma unroll
      for (int i = 0; i < 2; ++i)
#pragma unroll
        for (int cf = 0; cf < 4; ++cf)
          s[i][cf] = __builtin_amdgcn_mfma_f32_16x16x32_bf16(qf[i][kk], kf[cf], s[i][cf], 0, 0, 0);
    }

    // --- causal mask (diagonal tiles only) ---
    if (kb + 63 > wrow0) {
#pragma unroll
      for (int i = 0; i < 2; ++i)
#pragma unroll
        for (int cf = 0; cf < 4; ++cf) {
          int key = kb + cf * 16 + r;
#pragma unroll
          for (int reg = 0; reg < 4; ++reg) {
            int rowg = wrow0 + i * 16 + g * 4 + reg;
            if (key > rowg) s[i][cf][reg] = -1e30f;
          }
        }
    }

    // --- online softmax; P -> LDS (bf16, swizzled) ---
#pragma unroll
    for (int i = 0; i < 2; ++i) {
      f32x4 alv;
#pragma unroll
      for (int reg = 0; reg < 4; ++reg) {
        float v = fmaxf(fmaxf(s[i][0][reg], s[i][1][reg]),
                        fmaxf(s[i][2][reg], s[i][3][reg]));
        v = fmaxf(v, __shfl_xor(v, 1));
        v = fmaxf(v, __shfl_xor(v, 2));
        v = fmaxf(v, __shfl_xor(v, 4));
        v = fmaxf(v, __shfl_xor(v, 8));
        float mo = m[i][reg];
        float mn = fmaxf(mo, v);
        float al = __builtin_amdgcn_exp2f((mo - mn) * cs);
        m[i][reg] = mn;
        float ps = 0.f;
        int rowp = i * 16 + g * 4 + reg;
        char* prow = (char*)Pw + rowp * 128;
        int sw = (rowp & 7) << 4;
#pragma unroll
        for (int cf = 0; cf < 4; ++cf) {
          float p = __builtin_amdgcn_exp2f((s[i][cf][reg] - mn) * cs);
          ps += p;
          *reinterpret_cast<unsigned short*>(prow + (((cf * 16 + r) * 2) ^ sw)) = f2bf(p);
        }
        l[i][reg] = l[i][reg] * al + ps;   // per-lane partial (summed at end)
        alv[reg] = al;
      }
#pragma unroll
      for (int df = 0; df < 4; ++df) ov[i][df] *= alv;
    }

    // --- PV: O += P * V ---
#pragma unroll
    for (int kk = 0; kk < 2; ++kk) {
      bf16x8 pf[2], vf[4];
#pragma unroll
      for (int i = 0; i < 2; ++i) {
        int row = i * 16 + r;
        const char* p = (const char*)Pw + row * 128 + ((kk * 64 + g * 16) ^ ((r & 7) << 4));
        pf[i] = __builtin_bit_cast(bf16x8, *reinterpret_cast<const uint4*>(p));
      }
#pragma unroll
      for (int df = 0; df < 4; ++df) {
        int row = df * 16 + r;
        const char* p = (const char*)Vt + row * 128 + ((kk * 64 + g * 16) ^ ((r & 7) << 4));
        vf[df] = __builtin_bit_cast(bf16x8, *reinterpret_cast<const uint4*>(p));
      }
#pragma unroll
      for (int i = 0; i < 2; ++i)
#pragma unroll
        for (int df = 0; df < 4; ++df)
          ov[i][df] = __builtin_amdgcn_mfma_f32_16x16x32_bf16(pf[i], vf[df], ov[i][df], 0, 0, 0);
    }
  }

  // --- finalize: sum partial denominators over 16-lane group, write O ---
#pragma unroll
  for (int i = 0; i < 2; ++i)
#pragma unroll
    for (int reg = 0; reg < 4; ++reg) {
      float ls = l[i][reg];
      ls += __shfl_xor(ls, 1);
      ls += __shfl_xor(ls, 2);
      ls += __shfl_xor(ls, 4);
      ls += __shfl_xor(ls, 8);
      float inv = 1.f / ls;
      int rowg = wrow0 + i * 16 + g * 4 + reg;
      size_t ob = (size_t)(b * 2048 + rowg) * 1024 + h * 64;
#pragma unroll
      for (int df = 0; df < 4; ++df)
        O[ob + df * 16 + r] = f2bf(ov[i][df][reg] * inv);
    }
}

// ---------------------------------------------------------------------------
extern "C" void kernel_launch(void* const* d_in, const int* in_sizes, int n_in,
                              void* d_out, int out_size, void* d_ws, size_t ws_size,
                              hipStream_t stream)
{
  (void)in_sizes; (void)n_in; (void)out_size; (void)ws_size;
  const float* x    = (const float*)d_in[0];   // (B,T,D) f32
  const float* rope = (const float*)d_in[1];   // (T,32,2) f32
  const float* Wa   = (const float*)d_in[2];   // (D,3D) f32
  const float* Wp   = (const float*)d_in[3];   // (D,D) f32
  // d_in[4] = causal mask (ignored; recomputed)

  unsigned short* qkv = (unsigned short*)d_ws;             // 4096x3072 bf16
  unsigned short* Qb  = qkv + (size_t)4096 * 3072;         // (B,H,T,64) bf16
  unsigned short* Kb  = Qb + (size_t)32 * 2048 * 64;
  unsigned short* Vb  = Kb + (size_t)32 * 2048 * 64;
  unsigned short* O   = qkv;  // qkv region dead after rope kernel -> reuse
  float* out = (float*)d_out;

  gemm_kernel<true, false><<<dim3(3072 / 64, 4096 / 64), 256, 0, stream>>>(
      x, Wa, qkv, 4096, 3072, 1024);
  rope_scatter_kernel<<<(4096 * 3072 / 4) / 256, 256, 0, stream>>>(qkv, rope, Qb, Kb, Vb);
  attn_mfma_kernel<<<512, 256, 0, stream>>>(Qb, Kb, Vb, O);
  gemm_kernel<false, true><<<dim3(1024 / 64, 4096 / 64), 256, 0, stream>>>(
      O, Wp, out, 4096, 1024, 1024);
}

// Round 5
// 315.770 us; speedup vs baseline: 4.2734x; 1.3002x over previous
//
#include <hip/hip_runtime.h>

// B=2, T=2048, D=1024, H=16, HD=64.
// Inputs f32 (x, rope, W_attn, W_proj), mask ignored (causal recomputed).
// Output f32. Internal tensors bf16 in workspace.

typedef __bf16 bf16x8 __attribute__((ext_vector_type(8)));
typedef float f32x4 __attribute__((ext_vector_type(4)));

__device__ __forceinline__ float bf2f(unsigned short u) {
  unsigned int i = ((unsigned int)u) << 16;
  return __builtin_bit_cast(float, i);
}
__device__ __forceinline__ unsigned short f2bf(float f) {
  unsigned int i = __builtin_bit_cast(unsigned int, f);
  i += 0x7FFFu + ((i >> 16) & 1u);   // round-to-nearest-even
  return (unsigned short)(i >> 16);
}

// async global->LDS, 16B per lane (lds dest = wave base + lane*16)
__device__ __forceinline__ void gload_lds16(const unsigned short* g, unsigned short* l) {
  __builtin_amdgcn_global_load_lds(
      (const __attribute__((address_space(1))) void*)g,
      (__attribute__((address_space(3))) void*)l, 16, 0, 0);
}

// ---------------------------------------------------------------------------
// Elementwise f32 -> bf16 convert (8 elems/thread).
// ---------------------------------------------------------------------------
__global__ __launch_bounds__(256) void convert_f32_bf16_kernel(
    const float* __restrict__ in, unsigned short* __restrict__ outp, int n8)
{
  int i = blockIdx.x * 256 + threadIdx.x;
  if (i >= n8) return;
  const float4 a0 = *reinterpret_cast<const float4*>(&in[(size_t)i * 8]);
  const float4 a1 = *reinterpret_cast<const float4*>(&in[(size_t)i * 8 + 4]);
  uint4 pk;
  pk.x = (unsigned int)f2bf(a0.x) | ((unsigned int)f2bf(a0.y) << 16);
  pk.y = (unsigned int)f2bf(a0.z) | ((unsigned int)f2bf(a0.w) << 16);
  pk.z = (unsigned int)f2bf(a1.x) | ((unsigned int)f2bf(a1.y) << 16);
  pk.w = (unsigned int)f2bf(a1.z) | ((unsigned int)f2bf(a1.w) << 16);
  *reinterpret_cast<uint4*>(&outp[(size_t)i * 8]) = pk;
}

// ---------------------------------------------------------------------------
// Transpose + convert: W (R x C f32, row-major) -> WT (C x R bf16, row-major).
// 64x64 tiles via LDS.
// ---------------------------------------------------------------------------
__global__ __launch_bounds__(256) void convert_transpose_kernel(
    const float* __restrict__ W, unsigned short* __restrict__ WT, int R, int C)
{
  __shared__ unsigned short tileT[64][72];   // [c][r], padded
  const int c0 = blockIdx.x * 64, r0 = blockIdx.y * 64;
  const int tid = threadIdx.x;
  const int rr = tid >> 4, cc = (tid & 15) * 4;
#pragma unroll
  for (int it = 0; it < 4; ++it) {
    int gr = r0 + rr + it * 16;
    float4 v = *reinterpret_cast<const float4*>(&W[(size_t)gr * C + c0 + cc]);
    tileT[cc + 0][rr + it * 16] = f2bf(v.x);
    tileT[cc + 1][rr + it * 16] = f2bf(v.y);
    tileT[cc + 2][rr + it * 16] = f2bf(v.z);
    tileT[cc + 3][rr + it * 16] = f2bf(v.w);
  }
  __syncthreads();
  const int wc = tid >> 2, wk = (tid & 3) * 16;
  uint4 o0 = *reinterpret_cast<const uint4*>(&tileT[wc][wk]);
  uint4 o1 = *reinterpret_cast<const uint4*>(&tileT[wc][wk + 8]);
  unsigned short* dst = &WT[(size_t)(c0 + wc) * R + r0 + wk];
  *reinterpret_cast<uint4*>(dst) = o0;
  *reinterpret_cast<uint4*>(dst + 8) = o1;
}

// ---------------------------------------------------------------------------
// m97-style GEMM: C(MxN) = A(MxK) * BT(NxK)^T, all bf16, f32 accumulate.
// 128x128 tile, BK=32, 4 waves (2x2), each wave 64x64 via 4x4 16x16x32 MFMA.
// global_load_lds width-16 staging into linear LDS [row][k] (64B rows).
// ---------------------------------------------------------------------------
template<bool C_IS_F32>
__global__ __launch_bounds__(256) void gemm_bt_kernel(
    const unsigned short* __restrict__ A, const unsigned short* __restrict__ BT,
    void* __restrict__ Cp, int M, int N, int K)
{
  __shared__ alignas(16) unsigned short As[128 * 32];
  __shared__ alignas(16) unsigned short Bs[128 * 32];

  const int tid = threadIdx.x;
  const int m0 = blockIdx.y * 128, n0 = blockIdx.x * 128;
  const int w = tid >> 6, lane = tid & 63;
  const int wr = (w >> 1) * 64, wc = (w & 1) * 64;
  const int g = lane >> 4, r = lane & 15;

  f32x4 acc[4][4];
#pragma unroll
  for (int i = 0; i < 4; ++i)
#pragma unroll
    for (int j = 0; j < 4; ++j)
      acc[i][j] = f32x4{0.f, 0.f, 0.f, 0.f};

  // staging: wave w covers LDS elements [w*1024, w*1024+1024) per issue-pair
  // lane's element = w*1024 + issue*512 + lane*8 -> row = w*32+issue*16+(lane>>2), k=(lane&3)*8
  const int srow = w * 32 + (lane >> 2);
  const int sk = (lane & 3) * 8;
  const size_t a_base = (size_t)(m0 + srow) * K + sk;
  const size_t b_base = (size_t)(n0 + srow) * K + sk;
  unsigned short* lA = &As[w * 1024 + lane * 8];
  unsigned short* lB = &Bs[w * 1024 + lane * 8];
  const size_t rstep = (size_t)16 * K;

  for (int k0 = 0; k0 < K; k0 += 32) {
    __syncthreads();
    gload_lds16(&A[a_base + k0], lA);
    gload_lds16(&A[a_base + k0 + rstep], lA + 512);
    gload_lds16(&BT[b_base + k0], lB);
    gload_lds16(&BT[b_base + k0 + rstep], lB + 512);
    __syncthreads();

    bf16x8 af[4], bff[4];
#pragma unroll
    for (int i = 0; i < 4; ++i)
      af[i] = __builtin_bit_cast(bf16x8,
          *reinterpret_cast<const uint4*>(&As[(wr + i * 16 + r) * 32 + g * 8]));
#pragma unroll
    for (int j = 0; j < 4; ++j)
      bff[j] = __builtin_bit_cast(bf16x8,
          *reinterpret_cast<const uint4*>(&Bs[(wc + j * 16 + r) * 32 + g * 8]));
#pragma unroll
    for (int i = 0; i < 4; ++i)
#pragma unroll
      for (int j = 0; j < 4; ++j)
        acc[i][j] = __builtin_amdgcn_mfma_f32_16x16x32_bf16(af[i], bff[j], acc[i][j], 0, 0, 0);
  }

  // D layout: col = lane&15 (r), row = g*4 + reg
#pragma unroll
  for (int i = 0; i < 4; ++i)
#pragma unroll
    for (int j = 0; j < 4; ++j)
#pragma unroll
      for (int reg = 0; reg < 4; ++reg) {
        int row = m0 + wr + i * 16 + g * 4 + reg;
        int col = n0 + wc + j * 16 + r;
        if constexpr (C_IS_F32)
          ((float*)Cp)[(size_t)row * N + col] = acc[i][j][reg];
        else
          ((unsigned short*)Cp)[(size_t)row * N + col] = f2bf(acc[i][j][reg]);
      }
}

// ---------------------------------------------------------------------------
// RoPE + scatter: qkv bf16 (B,T,3D) -> Q,K (rope'd), V in (B,H,T,HD) bf16.
// ---------------------------------------------------------------------------
__global__ __launch_bounds__(256) void rope_scatter_kernel(
    const unsigned short* __restrict__ qkv, const float* __restrict__ rope,
    unsigned short* __restrict__ Qb, unsigned short* __restrict__ Kb,
    unsigned short* __restrict__ Vb)
{
  int gid = blockIdx.x * 256 + threadIdx.x;
  int rowM = gid / 768;
  int c4 = (gid - rowM * 768) * 4;
  int b = rowM >> 11, t = rowM & 2047;
  int sec = c4 >> 10;                         // 0=q 1=k 2=v
  int d = c4 & 1023;
  int h = d >> 6, hd = d & 63;

  uint2 vv = *reinterpret_cast<const uint2*>(&qkv[(size_t)rowM * 3072 + c4]);
  size_t dst = ((size_t)(b * 16 + h) * 2048 + t) * 64 + hd;

  if (sec == 2) {
    *reinterpret_cast<uint2*>(&Vb[dst]) = vv;
    return;
  }
  float x0 = bf2f((unsigned short)(vv.x & 0xffffu));
  float x1 = bf2f((unsigned short)(vv.x >> 16));
  float x2 = bf2f((unsigned short)(vv.y & 0xffffu));
  float x3 = bf2f((unsigned short)(vv.y >> 16));
  float4 rc = *reinterpret_cast<const float4*>(&rope[(size_t)t * 64 + hd]);
  float y0 = x0 * rc.x - x1 * rc.y;
  float y1 = x1 * rc.x + x0 * rc.y;
  float y2 = x2 * rc.z - x3 * rc.w;
  float y3 = x3 * rc.z + x2 * rc.w;
  uint2 outv;
  outv.x = (unsigned int)f2bf(y0) | ((unsigned int)f2bf(y1) << 16);
  outv.y = (unsigned int)f2bf(y2) | ((unsigned int)f2bf(y3) << 16);
  unsigned short* dstp = (sec == 0) ? Qb : Kb;
  *reinterpret_cast<uint2*>(&dstp[dst]) = outv;
}

// ---------------------------------------------------------------------------
// MFMA causal flash attention. Q/K/V bf16 (B,H,T,64); O bf16 (B,T,D).
// 256 threads = 4 waves. Q-tile 128 rows (32/wave). K-tile 64 keys.
// All LDS tiles [64][64] bf16 with T2 XOR swizzle: byte ^= (row&7)<<4.
// ---------------------------------------------------------------------------
__global__ __launch_bounds__(256) void attn_mfma_kernel(
    const unsigned short* __restrict__ Q, const unsigned short* __restrict__ K,
    const unsigned short* __restrict__ V, unsigned short* __restrict__ O)
{
  __shared__ unsigned short Ks[64 * 64];     // [key][d] swizzled
  __shared__ unsigned short Vt[64 * 64];     // [d][key] swizzled (transposed)
  __shared__ unsigned short Ps[4][32 * 64];  // per-wave P [row][key] swizzled

  const int bx = blockIdx.x;
  const int idx = bx & 255, hi = bx >> 8;
  const int bh = hi * 16 + (idx >> 4);
  const int tp = idx & 15;
  const int tile = hi ? tp : 15 - tp;        // complementary work pairing
  const int b = bh >> 4, h = bh & 15;
  const size_t base = (size_t)bh * 2048 * 64;

  const int tid = threadIdx.x, w = tid >> 6, lane = tid & 63;
  const int g = lane >> 4, r = lane & 15;
  const int q0 = tile * 128;
  const int wrow0 = q0 + w * 32;

  bf16x8 qf[2][2];
#pragma unroll
  for (int i = 0; i < 2; ++i)
#pragma unroll
    for (int kk = 0; kk < 2; ++kk)
      qf[i][kk] = __builtin_bit_cast(bf16x8, *reinterpret_cast<const uint4*>(
          &Q[base + (size_t)(wrow0 + i * 16 + r) * 64 + kk * 32 + g * 8]));

  float m[2][4], l[2][4];
  f32x4 ov[2][4];
#pragma unroll
  for (int i = 0; i < 2; ++i) {
#pragma unroll
    for (int reg = 0; reg < 4; ++reg) { m[i][reg] = -1e30f; l[i][reg] = 0.f; }
#pragma unroll
    for (int df = 0; df < 4; ++df) ov[i][df] = f32x4{0.f, 0.f, 0.f, 0.f};
  }

  unsigned short* Pw = &Ps[w][0];
  const float cs = 0.125f * 1.44269504f;
  const int nkt = (q0 >> 6) + 2;

  for (int c = 0; c < nkt; ++c) {
    const int kb = c * 64;
    __syncthreads();
    {
      const int c8 = (tid & 7) * 8;
      int row = tid >> 3;
#pragma unroll
      for (int it = 0; it < 2; ++it, row += 32) {
        uint4 kv = *reinterpret_cast<const uint4*>(&K[base + (size_t)(kb + row) * 64 + c8]);
        char* p = (char*)Ks + row * 128 + ((c8 * 2) ^ ((row & 7) << 4));
        *reinterpret_cast<uint4*>(p) = kv;
      }
    }
    {
      const int d = tid & 63, kb16 = (tid >> 6) * 16;
      unsigned int pk[8];
#pragma unroll
      for (int j = 0; j < 8; ++j) {
        unsigned int lo  = V[base + (size_t)(kb + kb16 + 2 * j) * 64 + d];
        unsigned int hiu = V[base + (size_t)(kb + kb16 + 2 * j + 1) * 64 + d];
        pk[j] = lo | (hiu << 16);
      }
      char* pr = (char*)Vt + d * 128;
      int cA = (kb16 * 2) ^ ((d & 7) << 4);
      int cB = (kb16 * 2 + 16) ^ ((d & 7) << 4);
      *reinterpret_cast<uint4*>(pr + cA) = uint4{pk[0], pk[1], pk[2], pk[3]};
      *reinterpret_cast<uint4*>(pr + cB) = uint4{pk[4], pk[5], pk[6], pk[7]};
    }
    __syncthreads();

    if (kb > wrow0 + 31) continue;

    f32x4 s[2][4];
#pragma unroll
    for (int i = 0; i < 2; ++i)
#pragma unroll
      for (int cf = 0; cf < 4; ++cf) s[i][cf] = f32x4{0.f, 0.f, 0.f, 0.f};
#pragma unroll
    for (int kk = 0; kk < 2; ++kk) {
      bf16x8 kf[4];
#pragma unroll
      for (int cf = 0; cf < 4; ++cf) {
        int row = cf * 16 + r;
        const char* p = (const char*)Ks + row * 128 + ((kk * 64 + g * 16) ^ ((r & 7) << 4));
        kf[cf] = __builtin_bit_cast(bf16x8, *reinterpret_cast<const uint4*>(p));
      }
#pragma unroll
      for (int i = 0; i < 2; ++i)
#pragma unroll
        for (int cf = 0; cf < 4; ++cf)
          s[i][cf] = __builtin_amdgcn_mfma_f32_16x16x32_bf16(qf[i][kk], kf[cf], s[i][cf], 0, 0, 0);
    }

    if (kb + 63 > wrow0) {
#pragma unroll
      for (int i = 0; i < 2; ++i)
#pragma unroll
        for (int cf = 0; cf < 4; ++cf) {
          int key = kb + cf * 16 + r;
#pragma unroll
          for (int reg = 0; reg < 4; ++reg) {
            int rowg = wrow0 + i * 16 + g * 4 + reg;
            if (key > rowg) s[i][cf][reg] = -1e30f;
          }
        }
    }

#pragma unroll
    for (int i = 0; i < 2; ++i) {
      f32x4 alv;
#pragma unroll
      for (int reg = 0; reg < 4; ++reg) {
        float v = fmaxf(fmaxf(s[i][0][reg], s[i][1][reg]),
                        fmaxf(s[i][2][reg], s[i][3][reg]));
        v = fmaxf(v, __shfl_xor(v, 1));
        v = fmaxf(v, __shfl_xor(v, 2));
        v = fmaxf(v, __shfl_xor(v, 4));
        v = fmaxf(v, __shfl_xor(v, 8));
        float mo = m[i][reg];
        float mn = fmaxf(mo, v);
        float al = __builtin_amdgcn_exp2f((mo - mn) * cs);
        m[i][reg] = mn;
        float ps = 0.f;
        int rowp = i * 16 + g * 4 + reg;
        char* prow = (char*)Pw + rowp * 128;
        int sw = (rowp & 7) << 4;
#pragma unroll
        for (int cf = 0; cf < 4; ++cf) {
          float p = __builtin_amdgcn_exp2f((s[i][cf][reg] - mn) * cs);
          ps += p;
          *reinterpret_cast<unsigned short*>(prow + (((cf * 16 + r) * 2) ^ sw)) = f2bf(p);
        }
        l[i][reg] = l[i][reg] * al + ps;
        alv[reg] = al;
      }
#pragma unroll
      for (int df = 0; df < 4; ++df) ov[i][df] *= alv;
    }

#pragma unroll
    for (int kk = 0; kk < 2; ++kk) {
      bf16x8 pf[2], vf[4];
#pragma unroll
      for (int i = 0; i < 2; ++i) {
        int row = i * 16 + r;
        const char* p = (const char*)Pw + row * 128 + ((kk * 64 + g * 16) ^ ((r & 7) << 4));
        pf[i] = __builtin_bit_cast(bf16x8, *reinterpret_cast<const uint4*>(p));
      }
#pragma unroll
      for (int df = 0; df < 4; ++df) {
        int row = df * 16 + r;
        const char* p = (const char*)Vt + row * 128 + ((kk * 64 + g * 16) ^ ((r & 7) << 4));
        vf[df] = __builtin_bit_cast(bf16x8, *reinterpret_cast<const uint4*>(p));
      }
#pragma unroll
      for (int i = 0; i < 2; ++i)
#pragma unroll
        for (int df = 0; df < 4; ++df)
          ov[i][df] = __builtin_amdgcn_mfma_f32_16x16x32_bf16(pf[i], vf[df], ov[i][df], 0, 0, 0);
    }
  }

#pragma unroll
  for (int i = 0; i < 2; ++i)
#pragma unroll
    for (int reg = 0; reg < 4; ++reg) {
      float ls = l[i][reg];
      ls += __shfl_xor(ls, 1);
      ls += __shfl_xor(ls, 2);
      ls += __shfl_xor(ls, 4);
      ls += __shfl_xor(ls, 8);
      float inv = 1.f / ls;
      int rowg = wrow0 + i * 16 + g * 4 + reg;
      size_t ob = (size_t)(b * 2048 + rowg) * 1024 + h * 64;
#pragma unroll
      for (int df = 0; df < 4; ++df)
        O[ob + df * 16 + r] = f2bf(ov[i][df][reg] * inv);
    }
}

// ---------------------------------------------------------------------------
extern "C" void kernel_launch(void* const* d_in, const int* in_sizes, int n_in,
                              void* d_out, int out_size, void* d_ws, size_t ws_size,
                              hipStream_t stream)
{
  (void)in_sizes; (void)n_in; (void)out_size; (void)ws_size;
  const float* x    = (const float*)d_in[0];   // (B,T,D) f32
  const float* rope = (const float*)d_in[1];   // (T,32,2) f32
  const float* Wa   = (const float*)d_in[2];   // (D,3D) f32
  const float* Wp   = (const float*)d_in[3];   // (D,D) f32
  // d_in[4] = causal mask (ignored; recomputed)

  unsigned short* ws  = (unsigned short*)d_ws;
  unsigned short* qkv = ws;                                // 12,582,912
  unsigned short* Qb  = qkv + (size_t)4096 * 3072;         // 4,194,304
  unsigned short* Kb  = Qb + (size_t)32 * 2048 * 64;       // 4,194,304
  unsigned short* Vb  = Kb + (size_t)32 * 2048 * 64;       // 4,194,304
  unsigned short* WpT = Vb + (size_t)32 * 2048 * 64;       // 1,048,576
  unsigned short* xb  = Qb;   // alias: xb dead before rope writes Qb
  unsigned short* WaT = Kb;   // alias: WaT dead before rope writes Kb
  unsigned short* O   = qkv;  // alias: qkv dead after rope
  float* out = (float*)d_out;

  convert_f32_bf16_kernel<<<2048, 256, 0, stream>>>(x, xb, 4096 * 1024 / 8);
  convert_transpose_kernel<<<dim3(48, 16), 256, 0, stream>>>(Wa, WaT, 1024, 3072);
  convert_transpose_kernel<<<dim3(16, 16), 256, 0, stream>>>(Wp, WpT, 1024, 1024);
  gemm_bt_kernel<false><<<dim3(3072 / 128, 4096 / 128), 256, 0, stream>>>(
      xb, WaT, qkv, 4096, 3072, 1024);
  rope_scatter_kernel<<<(4096 * 3072 / 4) / 256, 256, 0, stream>>>(qkv, rope, Qb, Kb, Vb);
  attn_mfma_kernel<<<512, 256, 0, stream>>>(Qb, Kb, Vb, O);
  gemm_bt_kernel<true><<<dim3(1024 / 128, 4096 / 128), 256, 0, stream>>>(
      O, WpT, out, 4096, 1024, 1024);
}

// Round 6
// 233.280 us; speedup vs baseline: 5.7845x; 1.3536x over previous
//
#include <hip/hip_runtime.h>

// B=2, T=2048, D=1024, H=16, HD=64.
// Inputs f32 (x, rope, W_attn, W_proj), mask ignored (causal recomputed).
// Output f32. Internal tensors bf16 in workspace.

typedef __bf16 bf16x8 __attribute__((ext_vector_type(8)));
typedef float f32x4 __attribute__((ext_vector_type(4)));

__device__ __forceinline__ float bf2f(unsigned short u) {
  unsigned int i = ((unsigned int)u) << 16;
  return __builtin_bit_cast(float, i);
}
__device__ __forceinline__ unsigned short f2bf(float f) {
  unsigned int i = __builtin_bit_cast(unsigned int, f);
  i += 0x7FFFu + ((i >> 16) & 1u);   // round-to-nearest-even
  return (unsigned short)(i >> 16);
}

// async global->LDS, 16B per lane (lds dest = wave base + lane*16)
__device__ __forceinline__ void gload_lds16(const unsigned short* g, unsigned short* l) {
  __builtin_amdgcn_global_load_lds(
      (const __attribute__((address_space(1))) void*)g,
      (__attribute__((address_space(3))) void*)l, 16, 0, 0);
}

// ---------------------------------------------------------------------------
// Elementwise f32 -> bf16 convert (8 elems/thread).
// ---------------------------------------------------------------------------
__global__ __launch_bounds__(256) void convert_f32_bf16_kernel(
    const float* __restrict__ in, unsigned short* __restrict__ outp, int n8)
{
  int i = blockIdx.x * 256 + threadIdx.x;
  if (i >= n8) return;
  const float4 a0 = *reinterpret_cast<const float4*>(&in[(size_t)i * 8]);
  const float4 a1 = *reinterpret_cast<const float4*>(&in[(size_t)i * 8 + 4]);
  uint4 pk;
  pk.x = (unsigned int)f2bf(a0.x) | ((unsigned int)f2bf(a0.y) << 16);
  pk.y = (unsigned int)f2bf(a0.z) | ((unsigned int)f2bf(a0.w) << 16);
  pk.z = (unsigned int)f2bf(a1.x) | ((unsigned int)f2bf(a1.y) << 16);
  pk.w = (unsigned int)f2bf(a1.z) | ((unsigned int)f2bf(a1.w) << 16);
  *reinterpret_cast<uint4*>(&outp[(size_t)i * 8]) = pk;
}

// ---------------------------------------------------------------------------
// Transpose + convert: W (R x C f32, row-major) -> WT (C x R bf16, row-major).
// ---------------------------------------------------------------------------
__global__ __launch_bounds__(256) void convert_transpose_kernel(
    const float* __restrict__ W, unsigned short* __restrict__ WT, int R, int C)
{
  __shared__ unsigned short tileT[64][72];   // [c][r], padded
  const int c0 = blockIdx.x * 64, r0 = blockIdx.y * 64;
  const int tid = threadIdx.x;
  const int rr = tid >> 4, cc = (tid & 15) * 4;
#pragma unroll
  for (int it = 0; it < 4; ++it) {
    int gr = r0 + rr + it * 16;
    float4 v = *reinterpret_cast<const float4*>(&W[(size_t)gr * C + c0 + cc]);
    tileT[cc + 0][rr + it * 16] = f2bf(v.x);
    tileT[cc + 1][rr + it * 16] = f2bf(v.y);
    tileT[cc + 2][rr + it * 16] = f2bf(v.z);
    tileT[cc + 3][rr + it * 16] = f2bf(v.w);
  }
  __syncthreads();
  const int wc = tid >> 2, wk = (tid & 3) * 16;
  uint4 o0 = *reinterpret_cast<const uint4*>(&tileT[wc][wk]);
  uint4 o1 = *reinterpret_cast<const uint4*>(&tileT[wc][wk + 8]);
  unsigned short* dst = &WT[(size_t)(c0 + wc) * R + r0 + wk];
  *reinterpret_cast<uint4*>(dst) = o0;
  *reinterpret_cast<uint4*>(dst + 8) = o1;
}

// ---------------------------------------------------------------------------
// bf16 transpose per head: Vb (BH, T, 64) -> VT (BH, 64, T). 64x64 tiles.
// ---------------------------------------------------------------------------
__global__ __launch_bounds__(256) void transpose_v_kernel(
    const unsigned short* __restrict__ Vb, unsigned short* __restrict__ VT)
{
  __shared__ unsigned short tl[64][72];
  const int bh = blockIdx.y;
  const int t0 = blockIdx.x * 64;
  const int tid = threadIdx.x;
  const unsigned short* src = Vb + (size_t)bh * 2048 * 64;
  unsigned short* dst = VT + (size_t)bh * 64 * 2048;
  int row = tid >> 3, c8 = (tid & 7) * 8;
#pragma unroll
  for (int it = 0; it < 2; ++it, row += 32) {
    uint4 v = *reinterpret_cast<const uint4*>(&src[(size_t)(t0 + row) * 64 + c8]);
    *reinterpret_cast<uint4*>(&tl[row][c8]) = v;
  }
  __syncthreads();
  const int d = tid >> 2, tc = (tid & 3) * 16;
  unsigned int o[8];
#pragma unroll
  for (int j = 0; j < 8; ++j) {
    unsigned int lo  = tl[tc + 2 * j][d];
    unsigned int hi2 = tl[tc + 2 * j + 1][d];
    o[j] = lo | (hi2 << 16);
  }
  unsigned short* dp = &dst[(size_t)d * 2048 + t0 + tc];
  *reinterpret_cast<uint4*>(dp)     = uint4{o[0], o[1], o[2], o[3]};
  *reinterpret_cast<uint4*>(dp + 8) = uint4{o[4], o[5], o[6], o[7]};
}

// ---------------------------------------------------------------------------
// m97-style GEMM: C(MxN) = A(MxK) * BT(NxK)^T, all bf16, f32 accumulate.
// 128x128 tile, BK=32, 4 waves (2x2), each wave 64x64 via 4x4 16x16x32 MFMA.
// ---------------------------------------------------------------------------
template<bool C_IS_F32>
__global__ __launch_bounds__(256) void gemm_bt_kernel(
    const unsigned short* __restrict__ A, const unsigned short* __restrict__ BT,
    void* __restrict__ Cp, int M, int N, int K)
{
  __shared__ alignas(16) unsigned short As[128 * 32];
  __shared__ alignas(16) unsigned short Bs[128 * 32];

  const int tid = threadIdx.x;
  const int m0 = blockIdx.y * 128, n0 = blockIdx.x * 128;
  const int w = tid >> 6, lane = tid & 63;
  const int wr = (w >> 1) * 64, wc = (w & 1) * 64;
  const int g = lane >> 4, r = lane & 15;

  f32x4 acc[4][4];
#pragma unroll
  for (int i = 0; i < 4; ++i)
#pragma unroll
    for (int j = 0; j < 4; ++j)
      acc[i][j] = f32x4{0.f, 0.f, 0.f, 0.f};

  const int srow = w * 32 + (lane >> 2);
  const int sk = (lane & 3) << 3;
  const size_t a_base = (size_t)(m0 + srow) * K + sk;
  const size_t b_base = (size_t)(n0 + srow) * K + sk;
  unsigned short* lA = &As[w * 1024 + lane * 8];
  unsigned short* lB = &Bs[w * 1024 + lane * 8];
  const size_t rstep = (size_t)16 * K;

  for (int k0 = 0; k0 < K; k0 += 32) {
    __syncthreads();
    gload_lds16(&A[a_base + k0], lA);
    gload_lds16(&A[a_base + k0 + rstep], lA + 512);
    gload_lds16(&BT[b_base + k0], lB);
    gload_lds16(&BT[b_base + k0 + rstep], lB + 512);
    __syncthreads();

    bf16x8 af[4], bff[4];
#pragma unroll
    for (int i = 0; i < 4; ++i)
      af[i] = __builtin_bit_cast(bf16x8,
          *reinterpret_cast<const uint4*>(&As[(wr + i * 16 + r) * 32 + g * 8]));
#pragma unroll
    for (int j = 0; j < 4; ++j)
      bff[j] = __builtin_bit_cast(bf16x8,
          *reinterpret_cast<const uint4*>(&Bs[(wc + j * 16 + r) * 32 + g * 8]));
#pragma unroll
    for (int i = 0; i < 4; ++i)
#pragma unroll
      for (int j = 0; j < 4; ++j)
        acc[i][j] = __builtin_amdgcn_mfma_f32_16x16x32_bf16(af[i], bff[j], acc[i][j], 0, 0, 0);
  }

#pragma unroll
  for (int i = 0; i < 4; ++i)
#pragma unroll
    for (int j = 0; j < 4; ++j)
#pragma unroll
      for (int reg = 0; reg < 4; ++reg) {
        int row = m0 + wr + i * 16 + g * 4 + reg;
        int col = n0 + wc + j * 16 + r;
        if constexpr (C_IS_F32)
          ((float*)Cp)[(size_t)row * N + col] = acc[i][j][reg];
        else
          ((unsigned short*)Cp)[(size_t)row * N + col] = f2bf(acc[i][j][reg]);
      }
}

// ---------------------------------------------------------------------------
// RoPE + scatter: qkv bf16 (B,T,3D) -> Q,K (rope'd), V in (B,H,T,HD) bf16.
// ---------------------------------------------------------------------------
__global__ __launch_bounds__(256) void rope_scatter_kernel(
    const unsigned short* __restrict__ qkv, const float* __restrict__ rope,
    unsigned short* __restrict__ Qb, unsigned short* __restrict__ Kb,
    unsigned short* __restrict__ Vb)
{
  int gid = blockIdx.x * 256 + threadIdx.x;
  int rowM = gid / 768;
  int c4 = (gid - rowM * 768) * 4;
  int b = rowM >> 11, t = rowM & 2047;
  int sec = c4 >> 10;                         // 0=q 1=k 2=v
  int d = c4 & 1023;
  int h = d >> 6, hd = d & 63;

  uint2 vv = *reinterpret_cast<const uint2*>(&qkv[(size_t)rowM * 3072 + c4]);
  size_t dst = ((size_t)(b * 16 + h) * 2048 + t) * 64 + hd;

  if (sec == 2) {
    *reinterpret_cast<uint2*>(&Vb[dst]) = vv;
    return;
  }
  float x0 = bf2f((unsigned short)(vv.x & 0xffffu));
  float x1 = bf2f((unsigned short)(vv.x >> 16));
  float x2 = bf2f((unsigned short)(vv.y & 0xffffu));
  float x3 = bf2f((unsigned short)(vv.y >> 16));
  float4 rc = *reinterpret_cast<const float4*>(&rope[(size_t)t * 64 + hd]);
  float y0 = x0 * rc.x - x1 * rc.y;
  float y1 = x1 * rc.x + x0 * rc.y;
  float y2 = x2 * rc.z - x3 * rc.w;
  float y3 = x3 * rc.z + x2 * rc.w;
  uint2 outv;
  outv.x = (unsigned int)f2bf(y0) | ((unsigned int)f2bf(y1) << 16);
  outv.y = (unsigned int)f2bf(y2) | ((unsigned int)f2bf(y3) << 16);
  unsigned short* dstp = (sec == 0) ? Qb : Kb;
  *reinterpret_cast<uint2*>(&dstp[dst]) = outv;
}

// ---------------------------------------------------------------------------
// MFMA causal flash attention, 8 waves (512 thr), double-buffered staging.
// Q/K bf16 (B,H,T,64); VT bf16 (B,H,64,T); O bf16 (B,T,D).
// Q-tile 128 rows (16/wave). K-tile 64 keys. T2 XOR swizzle on all LDS tiles.
// T14: next-tile global loads issued before compute, LDS writes after.
// ---------------------------------------------------------------------------
__global__ __launch_bounds__(512, 4) void attn_mfma_kernel(
    const unsigned short* __restrict__ Q, const unsigned short* __restrict__ K,
    const unsigned short* __restrict__ VT, unsigned short* __restrict__ O)
{
  __shared__ unsigned short Ks[2][64 * 64];  // [key][d] swizzled, dbuf
  __shared__ unsigned short Vs[2][64 * 64];  // [d][key] swizzled, dbuf
  __shared__ unsigned short Ps[8][16 * 64];  // per-wave P [row][key] swizzled

  const int bx = blockIdx.x;
  const int idx = bx & 255, hi = bx >> 8;
  const int bh = hi * 16 + (idx >> 4);
  const int tp = idx & 15;
  const int tile = hi ? tp : 15 - tp;        // complementary work pairing
  const int b = bh >> 4, h = bh & 15;
  const size_t base = (size_t)bh * 2048 * 64;
  const unsigned short* VTb = VT + (size_t)bh * 64 * 2048;

  const int tid = threadIdx.x, w = tid >> 6, lane = tid & 63;
  const int g = lane >> 4, r = lane & 15;
  const int q0 = tile * 128;
  const int wrow0 = q0 + w * 16;             // wave's 16 q-rows

  bf16x8 qf[2];
#pragma unroll
  for (int kk = 0; kk < 2; ++kk)
    qf[kk] = __builtin_bit_cast(bf16x8, *reinterpret_cast<const uint4*>(
        &Q[base + (size_t)(wrow0 + r) * 64 + kk * 32 + g * 8]));

  float m[4], l[4];
  f32x4 ov[4];
#pragma unroll
  for (int reg = 0; reg < 4; ++reg) { m[reg] = -1e30f; l[reg] = 0.f; }
#pragma unroll
  for (int df = 0; df < 4; ++df) ov[df] = f32x4{0.f, 0.f, 0.f, 0.f};

  // staging: thread loads one uint4 of K and one of VT per tile
  const int srow = tid >> 3, sc8 = (tid & 7) * 8;
  const unsigned short* Kg = &K[base + (size_t)srow * 64 + sc8];
  const unsigned short* Vg = &VTb[(size_t)srow * 2048 + sc8];
  const int sb = srow * 128 + ((sc8 * 2) ^ ((srow & 7) << 4));

  unsigned short* Pw = &Ps[w][0];
  const float cs = 0.125f * 1.44269504f;
  const int nkt = (q0 >> 6) + 2;

  // prologue: stage tile 0
  uint4 kreg = *reinterpret_cast<const uint4*>(Kg);
  uint4 vreg = *reinterpret_cast<const uint4*>(Vg);
  *reinterpret_cast<uint4*>((char*)Ks[0] + sb) = kreg;
  *reinterpret_cast<uint4*>((char*)Vs[0] + sb) = vreg;
  __syncthreads();

  for (int c = 0; c < nkt; ++c) {
    const int kb = c * 64;
    const int cur = c & 1;
    const bool pfn = (c + 1 < nkt);
    if (pfn) {   // issue next-tile loads early (latency hides under compute)
      kreg = *reinterpret_cast<const uint4*>(Kg + (size_t)(kb + 64) * 64);
      vreg = *reinterpret_cast<const uint4*>(Vg + kb + 64);
    }

    if (kb <= wrow0 + 15) {
      // --- QK^T ---
      f32x4 s[4];
#pragma unroll
      for (int cf = 0; cf < 4; ++cf) s[cf] = f32x4{0.f, 0.f, 0.f, 0.f};
      __builtin_amdgcn_s_setprio(1);
#pragma unroll
      for (int kk = 0; kk < 2; ++kk) {
#pragma unroll
        for (int cf = 0; cf < 4; ++cf) {
          int row = cf * 16 + r;
          const char* p = (const char*)Ks[cur] + row * 128 + ((kk * 64 + g * 16) ^ ((r & 7) << 4));
          bf16x8 kf = __builtin_bit_cast(bf16x8, *reinterpret_cast<const uint4*>(p));
          s[cf] = __builtin_amdgcn_mfma_f32_16x16x32_bf16(qf[kk], kf, s[cf], 0, 0, 0);
        }
      }
      __builtin_amdgcn_s_setprio(0);

      // --- causal mask (diagonal tiles only) ---
      if (kb + 63 > wrow0) {
#pragma unroll
        for (int cf = 0; cf < 4; ++cf) {
          int key = kb + cf * 16 + r;
#pragma unroll
          for (int reg = 0; reg < 4; ++reg) {
            int rowg = wrow0 + g * 4 + reg;
            if (key > rowg) s[cf][reg] = -1e30f;
          }
        }
      }

      // --- online softmax; P -> LDS (bf16, swizzled) ---
      f32x4 alv;
#pragma unroll
      for (int reg = 0; reg < 4; ++reg) {
        float v = fmaxf(fmaxf(s[0][reg], s[1][reg]), fmaxf(s[2][reg], s[3][reg]));
        v = fmaxf(v, __shfl_xor(v, 1));
        v = fmaxf(v, __shfl_xor(v, 2));
        v = fmaxf(v, __shfl_xor(v, 4));
        v = fmaxf(v, __shfl_xor(v, 8));
        float mo = m[reg];
        float mn = fmaxf(mo, v);
        float al = __builtin_amdgcn_exp2f((mo - mn) * cs);
        m[reg] = mn;
        float ps = 0.f;
        int rowp = g * 4 + reg;
        char* prow = (char*)Pw + rowp * 128;
        int sw = (rowp & 7) << 4;
#pragma unroll
        for (int cf = 0; cf < 4; ++cf) {
          float p = __builtin_amdgcn_exp2f((s[cf][reg] - mn) * cs);
          ps += p;
          *reinterpret_cast<unsigned short*>(prow + (((cf * 16 + r) * 2) ^ sw)) = f2bf(p);
        }
        l[reg] = l[reg] * al + ps;
        alv[reg] = al;
      }
#pragma unroll
      for (int df = 0; df < 4; ++df) ov[df] *= alv;

      // --- PV ---
      __builtin_amdgcn_s_setprio(1);
#pragma unroll
      for (int kk = 0; kk < 2; ++kk) {
        const char* pp = (const char*)Pw + r * 128 + ((kk * 64 + g * 16) ^ ((r & 7) << 4));
        bf16x8 pf = __builtin_bit_cast(bf16x8, *reinterpret_cast<const uint4*>(pp));
#pragma unroll
        for (int df = 0; df < 4; ++df) {
          int row = df * 16 + r;
          const char* p = (const char*)Vs[cur] + row * 128 + ((kk * 64 + g * 16) ^ ((r & 7) << 4));
          bf16x8 vf = __builtin_bit_cast(bf16x8, *reinterpret_cast<const uint4*>(p));
          ov[df] = __builtin_amdgcn_mfma_f32_16x16x32_bf16(pf, vf, ov[df], 0, 0, 0);
        }
      }
      __builtin_amdgcn_s_setprio(0);
    }

    if (pfn) {   // write next tile into the other buffer
      *reinterpret_cast<uint4*>((char*)Ks[cur ^ 1] + sb) = kreg;
      *reinterpret_cast<uint4*>((char*)Vs[cur ^ 1] + sb) = vreg;
    }
    __syncthreads();
  }

  // --- finalize ---
#pragma unroll
  for (int reg = 0; reg < 4; ++reg) {
    float ls = l[reg];
    ls += __shfl_xor(ls, 1);
    ls += __shfl_xor(ls, 2);
    ls += __shfl_xor(ls, 4);
    ls += __shfl_xor(ls, 8);
    float inv = 1.f / ls;
    int rowg = wrow0 + g * 4 + reg;
    size_t ob = (size_t)(b * 2048 + rowg) * 1024 + h * 64;
#pragma unroll
    for (int df = 0; df < 4; ++df)
      O[ob + df * 16 + r] = f2bf(ov[df][reg] * inv);
  }
}

// ---------------------------------------------------------------------------
extern "C" void kernel_launch(void* const* d_in, const int* in_sizes, int n_in,
                              void* d_out, int out_size, void* d_ws, size_t ws_size,
                              hipStream_t stream)
{
  (void)in_sizes; (void)n_in; (void)out_size; (void)ws_size;
  const float* x    = (const float*)d_in[0];   // (B,T,D) f32
  const float* rope = (const float*)d_in[1];   // (T,32,2) f32
  const float* Wa   = (const float*)d_in[2];   // (D,3D) f32
  const float* Wp   = (const float*)d_in[3];   // (D,D) f32
  // d_in[4] = causal mask (ignored; recomputed)

  unsigned short* ws  = (unsigned short*)d_ws;
  unsigned short* qkv = ws;                                // 12.58M elems
  unsigned short* Qb  = qkv + (size_t)4096 * 3072;
  unsigned short* Kb  = Qb + (size_t)32 * 2048 * 64;
  unsigned short* Vb  = Kb + (size_t)32 * 2048 * 64;
  unsigned short* WpT = Vb + (size_t)32 * 2048 * 64;
  unsigned short* xb  = Qb;                      // alias: dead before rope writes Qb
  unsigned short* WaT = Kb;                      // alias: dead before rope writes Kb
  unsigned short* O   = qkv;                     // alias: qkv dead after rope
  unsigned short* VT  = qkv + (size_t)4096 * 1024;  // alias: disjoint from O region
  float* out = (float*)d_out;

  convert_f32_bf16_kernel<<<2048, 256, 0, stream>>>(x, xb, 4096 * 1024 / 8);
  convert_transpose_kernel<<<dim3(48, 16), 256, 0, stream>>>(Wa, WaT, 1024, 3072);
  convert_transpose_kernel<<<dim3(16, 16), 256, 0, stream>>>(Wp, WpT, 1024, 1024);
  gemm_bt_kernel<false><<<dim3(3072 / 128, 4096 / 128), 256, 0, stream>>>(
      xb, WaT, qkv, 4096, 3072, 1024);
  rope_scatter_kernel<<<(4096 * 3072 / 4) / 256, 256, 0, stream>>>(qkv, rope, Qb, Kb, Vb);
  transpose_v_kernel<<<dim3(32, 32), 256, 0, stream>>>(Vb, VT);
  attn_mfma_kernel<<<512, 512, 0, stream>>>(Qb, Kb, VT, O);
  gemm_bt_kernel<true><<<dim3(1024 / 128, 4096 / 128), 256, 0, stream>>>(
      O, WpT, out, 4096, 1024, 1024);
}

// Round 8
// 225.731 us; speedup vs baseline: 5.9779x; 1.0334x over previous
//
#include <hip/hip_runtime.h>

// B=2, T=2048, D=1024, H=16, HD=64.
// Inputs f32 (x, rope, W_attn, W_proj), mask ignored (causal recomputed).
// Output f32. Internal tensors bf16 in workspace.

typedef __bf16 bf16x8 __attribute__((ext_vector_type(8)));
typedef float f32x4 __attribute__((ext_vector_type(4)));

__device__ __forceinline__ float bf2f(unsigned short u) {
  unsigned int i = ((unsigned int)u) << 16;
  return __builtin_bit_cast(float, i);
}
__device__ __forceinline__ unsigned short f2bf(float f) {
  unsigned int i = __builtin_bit_cast(unsigned int, f);
  i += 0x7FFFu + ((i >> 16) & 1u);   // round-to-nearest-even
  return (unsigned short)(i >> 16);
}
__device__ __forceinline__ unsigned int pack2(float a, float b) {
  return (unsigned int)f2bf(a) | ((unsigned int)f2bf(b) << 16);
}

// async global->LDS, 16B per lane (lds dest = wave base + lane*16)
__device__ __forceinline__ void gload_lds16(const unsigned short* g, unsigned short* l) {
  __builtin_amdgcn_global_load_lds(
      (const __attribute__((address_space(1))) void*)g,
      (__attribute__((address_space(3))) void*)l, 16, 0, 0);
}

// ---------------------------------------------------------------------------
// Elementwise f32 -> bf16 convert (8 elems/thread).
// ---------------------------------------------------------------------------
__global__ __launch_bounds__(256) void convert_f32_bf16_kernel(
    const float* __restrict__ in, unsigned short* __restrict__ outp, int n8)
{
  int i = blockIdx.x * 256 + threadIdx.x;
  if (i >= n8) return;
  const float4 a0 = *reinterpret_cast<const float4*>(&in[(size_t)i * 8]);
  const float4 a1 = *reinterpret_cast<const float4*>(&in[(size_t)i * 8 + 4]);
  uint4 pk;
  pk.x = pack2(a0.x, a0.y);
  pk.y = pack2(a0.z, a0.w);
  pk.z = pack2(a1.x, a1.y);
  pk.w = pack2(a1.z, a1.w);
  *reinterpret_cast<uint4*>(&outp[(size_t)i * 8]) = pk;
}

// ---------------------------------------------------------------------------
// Transpose + convert: W (R x C f32, row-major) -> WT (C x R bf16, row-major).
// ---------------------------------------------------------------------------
__global__ __launch_bounds__(256) void convert_transpose_kernel(
    const float* __restrict__ W, unsigned short* __restrict__ WT, int R, int C)
{
  __shared__ unsigned short tileT[64][72];   // [c][r], padded
  const int c0 = blockIdx.x * 64, r0 = blockIdx.y * 64;
  const int tid = threadIdx.x;
  const int rr = tid >> 4, cc = (tid & 15) * 4;
#pragma unroll
  for (int it = 0; it < 4; ++it) {
    int gr = r0 + rr + it * 16;
    float4 v = *reinterpret_cast<const float4*>(&W[(size_t)gr * C + c0 + cc]);
    tileT[cc + 0][rr + it * 16] = f2bf(v.x);
    tileT[cc + 1][rr + it * 16] = f2bf(v.y);
    tileT[cc + 2][rr + it * 16] = f2bf(v.z);
    tileT[cc + 3][rr + it * 16] = f2bf(v.w);
  }
  __syncthreads();
  const int wc = tid >> 2, wk = (tid & 3) * 16;
  uint4 o0 = *reinterpret_cast<const uint4*>(&tileT[wc][wk]);
  uint4 o1 = *reinterpret_cast<const uint4*>(&tileT[wc][wk + 8]);
  unsigned short* dst = &WT[(size_t)(c0 + wc) * R + r0 + wk];
  *reinterpret_cast<uint4*>(dst) = o0;
  *reinterpret_cast<uint4*>(dst + 8) = o1;
}

// ---------------------------------------------------------------------------
// bf16 transpose per head: Vb (BH, T, 64) -> VT (BH, 64, T). 64x64 tiles.
// ---------------------------------------------------------------------------
__global__ __launch_bounds__(256) void transpose_v_kernel(
    const unsigned short* __restrict__ Vb, unsigned short* __restrict__ VT)
{
  __shared__ unsigned short tl[64][72];
  const int bh = blockIdx.y;
  const int t0 = blockIdx.x * 64;
  const int tid = threadIdx.x;
  const unsigned short* src = Vb + (size_t)bh * 2048 * 64;
  unsigned short* dst = VT + (size_t)bh * 64 * 2048;
  int row = tid >> 3, c8 = (tid & 7) * 8;
#pragma unroll
  for (int it = 0; it < 2; ++it, row += 32) {
    uint4 v = *reinterpret_cast<const uint4*>(&src[(size_t)(t0 + row) * 64 + c8]);
    *reinterpret_cast<uint4*>(&tl[row][c8]) = v;
  }
  __syncthreads();
  const int d = tid >> 2, tc = (tid & 3) * 16;
  unsigned int o[8];
#pragma unroll
  for (int j = 0; j < 8; ++j) {
    unsigned int lo  = tl[tc + 2 * j][d];
    unsigned int hi2 = tl[tc + 2 * j + 1][d];
    o[j] = lo | (hi2 << 16);
  }
  unsigned short* dp = &dst[(size_t)d * 2048 + t0 + tc];
  *reinterpret_cast<uint4*>(dp)     = uint4{o[0], o[1], o[2], o[3]};
  *reinterpret_cast<uint4*>(dp + 8) = uint4{o[4], o[5], o[6], o[7]};
}

// ---------------------------------------------------------------------------
// m97-style GEMM: C(MxN) = A(MxK) * BT(NxK)^T, all bf16, f32 accumulate.
// 128x128 tile, BK=32, 4 waves (2x2), each wave 64x64 via 4x4 16x16x32 MFMA.
// ---------------------------------------------------------------------------
template<bool C_IS_F32>
__global__ __launch_bounds__(256) void gemm_bt_kernel(
    const unsigned short* __restrict__ A, const unsigned short* __restrict__ BT,
    void* __restrict__ Cp, int M, int N, int K)
{
  __shared__ alignas(16) unsigned short As[128 * 32];
  __shared__ alignas(16) unsigned short Bs[128 * 32];

  const int tid = threadIdx.x;
  const int m0 = blockIdx.y * 128, n0 = blockIdx.x * 128;
  const int w = tid >> 6, lane = tid & 63;
  const int wr = (w >> 1) * 64, wc = (w & 1) * 64;
  const int g = lane >> 4, r = lane & 15;

  f32x4 acc[4][4];
#pragma unroll
  for (int i = 0; i < 4; ++i)
#pragma unroll
    for (int j = 0; j < 4; ++j)
      acc[i][j] = f32x4{0.f, 0.f, 0.f, 0.f};

  const int srow = w * 32 + (lane >> 2);
  const int sk = (lane & 3) << 3;
  const size_t a_base = (size_t)(m0 + srow) * K + sk;
  const size_t b_base = (size_t)(n0 + srow) * K + sk;
  unsigned short* lA = &As[w * 1024 + lane * 8];
  unsigned short* lB = &Bs[w * 1024 + lane * 8];
  const size_t rstep = (size_t)16 * K;

  for (int k0 = 0; k0 < K; k0 += 32) {
    __syncthreads();
    gload_lds16(&A[a_base + k0], lA);
    gload_lds16(&A[a_base + k0 + rstep], lA + 512);
    gload_lds16(&BT[b_base + k0], lB);
    gload_lds16(&BT[b_base + k0 + rstep], lB + 512);
    __syncthreads();

    bf16x8 af[4], bff[4];
#pragma unroll
    for (int i = 0; i < 4; ++i)
      af[i] = __builtin_bit_cast(bf16x8,
          *reinterpret_cast<const uint4*>(&As[(wr + i * 16 + r) * 32 + g * 8]));
#pragma unroll
    for (int j = 0; j < 4; ++j)
      bff[j] = __builtin_bit_cast(bf16x8,
          *reinterpret_cast<const uint4*>(&Bs[(wc + j * 16 + r) * 32 + g * 8]));
#pragma unroll
    for (int i = 0; i < 4; ++i)
#pragma unroll
      for (int j = 0; j < 4; ++j)
        acc[i][j] = __builtin_amdgcn_mfma_f32_16x16x32_bf16(af[i], bff[j], acc[i][j], 0, 0, 0);
  }

#pragma unroll
  for (int i = 0; i < 4; ++i)
#pragma unroll
    for (int j = 0; j < 4; ++j)
#pragma unroll
      for (int reg = 0; reg < 4; ++reg) {
        int row = m0 + wr + i * 16 + g * 4 + reg;
        int col = n0 + wc + j * 16 + r;
        if constexpr (C_IS_F32)
          ((float*)Cp)[(size_t)row * N + col] = acc[i][j][reg];
        else
          ((unsigned short*)Cp)[(size_t)row * N + col] = f2bf(acc[i][j][reg]);
      }
}

// ---------------------------------------------------------------------------
// RoPE + scatter: qkv bf16 (B,T,3D) -> Q,K (rope'd), V in (B,H,T,HD) bf16.
// ---------------------------------------------------------------------------
__global__ __launch_bounds__(256) void rope_scatter_kernel(
    const unsigned short* __restrict__ qkv, const float* __restrict__ rope,
    unsigned short* __restrict__ Qb, unsigned short* __restrict__ Kb,
    unsigned short* __restrict__ Vb)
{
  int gid = blockIdx.x * 256 + threadIdx.x;
  int rowM = gid / 768;
  int c4 = (gid - rowM * 768) * 4;
  int b = rowM >> 11, t = rowM & 2047;
  int sec = c4 >> 10;                         // 0=q 1=k 2=v
  int d = c4 & 1023;
  int h = d >> 6, hd = d & 63;

  uint2 vv = *reinterpret_cast<const uint2*>(&qkv[(size_t)rowM * 3072 + c4]);
  size_t dst = ((size_t)(b * 16 + h) * 2048 + t) * 64 + hd;

  if (sec == 2) {
    *reinterpret_cast<uint2*>(&Vb[dst]) = vv;
    return;
  }
  float x0 = bf2f((unsigned short)(vv.x & 0xffffu));
  float x1 = bf2f((unsigned short)(vv.x >> 16));
  float x2 = bf2f((unsigned short)(vv.y & 0xffffu));
  float x3 = bf2f((unsigned short)(vv.y >> 16));
  float4 rc = *reinterpret_cast<const float4*>(&rope[(size_t)t * 64 + hd]);
  float y0 = x0 * rc.x - x1 * rc.y;
  float y1 = x1 * rc.x + x0 * rc.y;
  float y2 = x2 * rc.z - x3 * rc.w;
  float y3 = x3 * rc.z + x2 * rc.w;
  uint2 outv;
  outv.x = pack2(y0, y1);
  outv.y = pack2(y2, y3);
  unsigned short* dstp = (sec == 0) ? Qb : Kb;
  *reinterpret_cast<uint2*>(&dstp[dst]) = outv;
}

// ---------------------------------------------------------------------------
// MFMA causal flash attention, 8 waves (512 thr), double-buffered staging,
// SWAPPED-OPERAND QK^T (S^T = mfma(K,Q)) so softmax state is per-lane scalar
// and P goes to PV's B-operand via 16 shuffles (no LDS roundtrip).
// Q/K bf16 (B,H,T,64); VT bf16 (B,H,64,T); O bf16 (B,T,D).
// Q-tile 128 rows (16/wave). K-tile 64 keys. T2 XOR swizzle on K/V LDS.
// ---------------------------------------------------------------------------
__global__ __launch_bounds__(512, 4) void attn_mfma_kernel(
    const unsigned short* __restrict__ Q, const unsigned short* __restrict__ K,
    const unsigned short* __restrict__ VT, unsigned short* __restrict__ O)
{
  __shared__ unsigned short Ks[2][64 * 64];  // [key][d] swizzled, dbuf
  __shared__ unsigned short Vs[2][64 * 64];  // [d][key] swizzled, dbuf

  const int bx = blockIdx.x;
  const int idx = bx & 255, hi = bx >> 8;
  const int bh = hi * 16 + (idx >> 4);
  const int tp = idx & 15;
  const int tile = hi ? tp : 15 - tp;        // complementary work pairing
  const int b = bh >> 4, h = bh & 15;
  const size_t base = (size_t)bh * 2048 * 64;
  const unsigned short* VTb = VT + (size_t)bh * 64 * 2048;

  const int tid = threadIdx.x, w = tid >> 6, lane = tid & 63;
  const int g = lane >> 4, r = lane & 15;
  const int q0 = tile * 128;
  const int wrow0 = q0 + w * 16;             // wave's 16 q-rows

  // Q as B-operand: col = q-row = wrow0+r, k = d = kk*32+g*8+j
  bf16x8 qf[2];
#pragma unroll
  for (int kk = 0; kk < 2; ++kk)
    qf[kk] = __builtin_bit_cast(bf16x8, *reinterpret_cast<const uint4*>(
        &Q[base + (size_t)(wrow0 + r) * 64 + kk * 32 + g * 8]));

  float m = -1e30f, l = 0.f;                 // per-lane scalar (q-row r)
  f32x4 ov[4];                               // O^T: row d = df*16+g*4+reg, col q=r
#pragma unroll
  for (int df = 0; df < 4; ++df) ov[df] = f32x4{0.f, 0.f, 0.f, 0.f};

  // staging: thread loads one uint4 of K and one of VT per tile
  const int srow = tid >> 3, sc8 = (tid & 7) * 8;
  const unsigned short* Kg = &K[base + (size_t)srow * 64 + sc8];
  const unsigned short* Vg = &VTb[(size_t)srow * 2048 + sc8];
  const int sb = srow * 128 + ((sc8 * 2) ^ ((srow & 7) << 4));

  const float cs = 0.125f * 1.44269504f;
  const int nkt = (q0 >> 6) + 2;

  // P-exchange sources (derived from key-bit remap, verified algebraically)
  const int srcA = ((g & 1) << 5) | r;       // lane (gs = 2*(g&1), r)
  const int srcB = srcA | 16;                // lane (gs = 2*(g&1)+1, r)
  const bool hsel = (g >> 1) != 0;

  // prologue: stage tile 0
  uint4 kreg = *reinterpret_cast<const uint4*>(Kg);
  uint4 vreg = *reinterpret_cast<const uint4*>(Vg);
  *reinterpret_cast<uint4*>((char*)Ks[0] + sb) = kreg;
  *reinterpret_cast<uint4*>((char*)Vs[0] + sb) = vreg;
  __syncthreads();

  for (int c = 0; c < nkt; ++c) {
    const int kb = c * 64;
    const int cur = c & 1;
    const bool pfn = (c + 1 < nkt);
    if (pfn) {   // issue next-tile loads early (latency hides under compute)
      kreg = *reinterpret_cast<const uint4*>(Kg + (size_t)(kb + 64) * 64);
      vreg = *reinterpret_cast<const uint4*>(Vg + kb + 64);
    }

    if (kb <= wrow0 + 15) {
      // --- QK^T swapped: s[cf] = S^T tile; lane holds S[key=kb+cf*16+g*4+reg][q=wrow0+r]
      f32x4 s[4];
#pragma unroll
      for (int cf = 0; cf < 4; ++cf) s[cf] = f32x4{0.f, 0.f, 0.f, 0.f};
      __builtin_amdgcn_s_setprio(1);
#pragma unroll
      for (int kk = 0; kk < 2; ++kk) {
#pragma unroll
        for (int cf = 0; cf < 4; ++cf) {
          int row = cf * 16 + r;
          const char* p = (const char*)Ks[cur] + row * 128 + ((kk * 64 + g * 16) ^ ((r & 7) << 4));
          bf16x8 kf = __builtin_bit_cast(bf16x8, *reinterpret_cast<const uint4*>(p));
          s[cf] = __builtin_amdgcn_mfma_f32_16x16x32_bf16(kf, qf[kk], s[cf], 0, 0, 0);
        }
      }
      __builtin_amdgcn_s_setprio(0);

      // --- causal mask (diagonal region only): key > q-row -> -inf
      if (kb + 63 > wrow0) {
#pragma unroll
        for (int cf = 0; cf < 4; ++cf) {
          int keyb = kb + cf * 16 + g * 4;
#pragma unroll
          for (int reg = 0; reg < 4; ++reg)
            if (keyb + reg > wrow0 + r) s[cf][reg] = -1e30f;
        }
      }

      // --- online softmax (per-lane scalar state, 2-shuffle row reduce) ---
      float vmx = s[0][0];
#pragma unroll
      for (int cf = 0; cf < 4; ++cf)
#pragma unroll
        for (int reg = 0; reg < 4; ++reg)
          vmx = fmaxf(vmx, s[cf][reg]);
      vmx = fmaxf(vmx, __shfl_xor(vmx, 16));
      vmx = fmaxf(vmx, __shfl_xor(vmx, 32));
      float mo = m;
      float mn = fmaxf(mo, vmx);
      float al = __builtin_amdgcn_exp2f((mo - mn) * cs);
      m = mn;
      float ps = 0.f;
#pragma unroll
      for (int cf = 0; cf < 4; ++cf)
#pragma unroll
        for (int reg = 0; reg < 4; ++reg) {
          float p = __builtin_amdgcn_exp2f((s[cf][reg] - mn) * cs);
          s[cf][reg] = p;
          ps += p;
        }
      l = l * al + ps;
#pragma unroll
      for (int df = 0; df < 4; ++df) ov[df] *= al;

      // pack P to bf16 u32 pairs: pk[cf][0]=keys(4g..4g+1), [1]=keys(4g+2..3)
      unsigned int pk[4][2];
#pragma unroll
      for (int cf = 0; cf < 4; ++cf) {
        pk[cf][0] = pack2(s[cf][0], s[cf][1]);
        pk[cf][1] = pack2(s[cf][2], s[cf][3]);
      }

      // --- exchange P into B-operand fragments + PV ---
      __builtin_amdgcn_s_setprio(1);
#pragma unroll
      for (int kk = 0; kk < 2; ++kk) {
        unsigned int a0 = __shfl(pk[2 * kk][0], srcA), b0 = __shfl(pk[2 * kk + 1][0], srcA);
        unsigned int a1 = __shfl(pk[2 * kk][1], srcA), b1 = __shfl(pk[2 * kk + 1][1], srcA);
        unsigned int a2 = __shfl(pk[2 * kk][0], srcB), b2 = __shfl(pk[2 * kk + 1][0], srcB);
        unsigned int a3 = __shfl(pk[2 * kk][1], srcB), b3 = __shfl(pk[2 * kk + 1][1], srcB);
        uint4 pw{ hsel ? b0 : a0, hsel ? b1 : a1, hsel ? b2 : a2, hsel ? b3 : a3 };
        bf16x8 pf = __builtin_bit_cast(bf16x8, pw);
#pragma unroll
        for (int df = 0; df < 4; ++df) {
          int row = df * 16 + r;
          const char* p = (const char*)Vs[cur] + row * 128 + ((kk * 64 + g * 16) ^ ((r & 7) << 4));
          bf16x8 vf = __builtin_bit_cast(bf16x8, *reinterpret_cast<const uint4*>(p));
          ov[df] = __builtin_amdgcn_mfma_f32_16x16x32_bf16(vf, pf, ov[df], 0, 0, 0);
        }
      }
      __builtin_amdgcn_s_setprio(0);
    }

    if (pfn) {   // write next tile into the other buffer
      *reinterpret_cast<uint4*>((char*)Ks[cur ^ 1] + sb) = kreg;
      *reinterpret_cast<uint4*>((char*)Vs[cur ^ 1] + sb) = vreg;
    }
    __syncthreads();
  }

  // --- finalize: l summed across the 4 g-lanes of this q-row ---
  float ls = l;
  ls += __shfl_xor(ls, 16);
  ls += __shfl_xor(ls, 32);
  float inv = 1.f / ls;
  size_t orow = (size_t)(b * 2048 + wrow0 + r) * 1024 + h * 64 + g * 4;
#pragma unroll
  for (int df = 0; df < 4; ++df) {
    uint2 o;
    o.x = pack2(ov[df][0] * inv, ov[df][1] * inv);
    o.y = pack2(ov[df][2] * inv, ov[df][3] * inv);
    *reinterpret_cast<uint2*>(&O[orow + df * 16]) = o;
  }
}

// ---------------------------------------------------------------------------
extern "C" void kernel_launch(void* const* d_in, const int* in_sizes, int n_in,
                              void* d_out, int out_size, void* d_ws, size_t ws_size,
                              hipStream_t stream)
{
  (void)in_sizes; (void)n_in; (void)out_size; (void)ws_size;
  const float* x    = (const float*)d_in[0];   // (B,T,D) f32
  const float* rope = (const float*)d_in[1];   // (T,32,2) f32
  const float* Wa   = (const float*)d_in[2];   // (D,3D) f32
  const float* Wp   = (const float*)d_in[3];   // (D,D) f32
  // d_in[4] = causal mask (ignored; recomputed)

  unsigned short* ws  = (unsigned short*)d_ws;
  unsigned short* qkv = ws;                                // 12.58M elems
  unsigned short* Qb  = qkv + (size_t)4096 * 3072;
  unsigned short* Kb  = Qb + (size_t)32 * 2048 * 64;
  unsigned short* Vb  = Kb + (size_t)32 * 2048 * 64;
  unsigned short* WpT = Vb + (size_t)32 * 2048 * 64;
  unsigned short* xb  = Qb;                      // alias: dead before rope writes Qb
  unsigned short* WaT = Kb;                      // alias: dead before rope writes Kb
  unsigned short* O   = qkv;                     // alias: qkv dead after rope
  unsigned short* VT  = qkv + (size_t)4096 * 1024;  // alias: disjoint from O region
  float* out = (float*)d_out;

  convert_f32_bf16_kernel<<<2048, 256, 0, stream>>>(x, xb, 4096 * 1024 / 8);
  convert_transpose_kernel<<<dim3(48, 16), 256, 0, stream>>>(Wa, WaT, 1024, 3072);
  convert_transpose_kernel<<<dim3(16, 16), 256, 0, stream>>>(Wp, WpT, 1024, 1024);
  gemm_bt_kernel<false><<<dim3(3072 / 128, 4096 / 128), 256, 0, stream>>>(
      xb, WaT, qkv, 4096, 3072, 1024);
  rope_scatter_kernel<<<(4096 * 3072 / 4) / 256, 256, 0, stream>>>(qkv, rope, Qb, Kb, Vb);
  transpose_v_kernel<<<dim3(32, 32), 256, 0, stream>>>(Vb, VT);
  attn_mfma_kernel<<<512, 512, 0, stream>>>(Qb, Kb, VT, O);
  gemm_bt_kernel<true><<<dim3(1024 / 128, 4096 / 128), 256, 0, stream>>>(
      O, WpT, out, 4096, 1024, 1024);
}

// Round 9
// 222.565 us; speedup vs baseline: 6.0629x; 1.0142x over previous
//
#include <hip/hip_runtime.h>

// B=2, T=2048, D=1024, H=16, HD=64.
// Inputs f32 (x, rope, W_attn, W_proj), mask ignored (causal recomputed).
// Output f32. Internal tensors bf16 in workspace.

typedef __bf16 bf16x8 __attribute__((ext_vector_type(8)));
typedef float f32x4 __attribute__((ext_vector_type(4)));

__device__ __forceinline__ float bf2f(unsigned short u) {
  unsigned int i = ((unsigned int)u) << 16;
  return __builtin_bit_cast(float, i);
}
__device__ __forceinline__ unsigned short f2bf(float f) {
  unsigned int i = __builtin_bit_cast(unsigned int, f);
  i += 0x7FFFu + ((i >> 16) & 1u);   // round-to-nearest-even
  return (unsigned short)(i >> 16);
}
__device__ __forceinline__ unsigned int pack2(float a, float b) {
  return (unsigned int)f2bf(a) | ((unsigned int)f2bf(b) << 16);
}
// hardware packed f32->bf16 (RNE), lo = a, hi = b  [T12 recipe]
__device__ __forceinline__ unsigned int cvtpk(float a, float b) {
  unsigned int r;
  asm("v_cvt_pk_bf16_f32 %0, %1, %2" : "=v"(r) : "v"(a), "v"(b));
  return r;
}

// async global->LDS, 16B per lane (lds dest = wave base + lane*16)
__device__ __forceinline__ void gload_lds16(const unsigned short* g, unsigned short* l) {
  __builtin_amdgcn_global_load_lds(
      (const __attribute__((address_space(1))) void*)g,
      (__attribute__((address_space(3))) void*)l, 16, 0, 0);
}

// ---------------------------------------------------------------------------
// Fused prep: [0,2048) convert x f32->bf16 ; [2048,2816) transpose Wa ;
// [2816,3072) transpose Wp. One launch instead of three.
// ---------------------------------------------------------------------------
__global__ __launch_bounds__(256) void prep_kernel(
    const float* __restrict__ x, unsigned short* __restrict__ xb,
    const float* __restrict__ Wa, unsigned short* __restrict__ WaT,
    const float* __restrict__ Wp, unsigned short* __restrict__ WpT)
{
  __shared__ unsigned short tileT[64][72];   // [c][r], padded
  const int bid = blockIdx.x, tid = threadIdx.x;

  if (bid < 2048) {             // ---- convert x (8 elems/thread) ----
    int i = bid * 256 + tid;
    const float4 a0 = *reinterpret_cast<const float4*>(&x[(size_t)i * 8]);
    const float4 a1 = *reinterpret_cast<const float4*>(&x[(size_t)i * 8 + 4]);
    uint4 pk;
    pk.x = pack2(a0.x, a0.y);
    pk.y = pack2(a0.z, a0.w);
    pk.z = pack2(a1.x, a1.y);
    pk.w = pack2(a1.z, a1.w);
    *reinterpret_cast<uint4*>(&xb[(size_t)i * 8]) = pk;
    return;
  }
  // ---- transpose+convert branch ----
  const float* W;
  unsigned short* WT;
  int R, C, c0, r0;
  if (bid < 2816) {
    int tb = bid - 2048;        // Wa: 48 x 16 tiles
    W = Wa; WT = WaT; R = 1024; C = 3072;
    c0 = (tb % 48) * 64; r0 = (tb / 48) * 64;
  } else {
    int tb = bid - 2816;        // Wp: 16 x 16 tiles
    W = Wp; WT = WpT; R = 1024; C = 1024;
    c0 = (tb % 16) * 64; r0 = (tb / 16) * 64;
  }
  const int rr = tid >> 4, cc = (tid & 15) * 4;
#pragma unroll
  for (int it = 0; it < 4; ++it) {
    int gr = r0 + rr + it * 16;
    float4 v = *reinterpret_cast<const float4*>(&W[(size_t)gr * C + c0 + cc]);
    tileT[cc + 0][rr + it * 16] = f2bf(v.x);
    tileT[cc + 1][rr + it * 16] = f2bf(v.y);
    tileT[cc + 2][rr + it * 16] = f2bf(v.z);
    tileT[cc + 3][rr + it * 16] = f2bf(v.w);
  }
  __syncthreads();
  const int wc = tid >> 2, wk = (tid & 3) * 16;
  uint4 o0 = *reinterpret_cast<const uint4*>(&tileT[wc][wk]);
  uint4 o1 = *reinterpret_cast<const uint4*>(&tileT[wc][wk + 8]);
  unsigned short* dst = &WT[(size_t)(c0 + wc) * R + r0 + wk];
  *reinterpret_cast<uint4*>(dst) = o0;
  *reinterpret_cast<uint4*>(dst + 8) = o1;
}

// ---------------------------------------------------------------------------
// bf16 transpose per head: Vb (BH, T, 64) -> VT (BH, 64, T). 64x64 tiles.
// ---------------------------------------------------------------------------
__global__ __launch_bounds__(256) void transpose_v_kernel(
    const unsigned short* __restrict__ Vb, unsigned short* __restrict__ VT)
{
  __shared__ unsigned short tl[64][72];
  const int bh = blockIdx.y;
  const int t0 = blockIdx.x * 64;
  const int tid = threadIdx.x;
  const unsigned short* src = Vb + (size_t)bh * 2048 * 64;
  unsigned short* dst = VT + (size_t)bh * 64 * 2048;
  int row = tid >> 3, c8 = (tid & 7) * 8;
#pragma unroll
  for (int it = 0; it < 2; ++it, row += 32) {
    uint4 v = *reinterpret_cast<const uint4*>(&src[(size_t)(t0 + row) * 64 + c8]);
    *reinterpret_cast<uint4*>(&tl[row][c8]) = v;
  }
  __syncthreads();
  const int d = tid >> 2, tc = (tid & 3) * 16;
  unsigned int o[8];
#pragma unroll
  for (int j = 0; j < 8; ++j) {
    unsigned int lo  = tl[tc + 2 * j][d];
    unsigned int hi2 = tl[tc + 2 * j + 1][d];
    o[j] = lo | (hi2 << 16);
  }
  unsigned short* dp = &dst[(size_t)d * 2048 + t0 + tc];
  *reinterpret_cast<uint4*>(dp)     = uint4{o[0], o[1], o[2], o[3]};
  *reinterpret_cast<uint4*>(dp + 8) = uint4{o[4], o[5], o[6], o[7]};
}

// ---------------------------------------------------------------------------
// m97-style GEMM: C(MxN) = A(MxK) * BT(NxK)^T, all bf16, f32 accumulate.
// 128x128 tile, BK=32, 4 waves (2x2), each wave 64x64 via 4x4 16x16x32 MFMA.
// bf16 output path: LDS-repack epilogue -> fully coalesced uint4 stores.
// ---------------------------------------------------------------------------
template<bool C_IS_F32>
__global__ __launch_bounds__(256) void gemm_bt_kernel(
    const unsigned short* __restrict__ A, const unsigned short* __restrict__ BT,
    void* __restrict__ Cp, int M, int N, int K)
{
  // K-loop uses first 16384 shorts (As 4096 + Bs 4096 at offsets 0 / 4096);
  // bf16 epilogue reuses all 16896 as a [128][132] bf16 C-tile.
  __shared__ alignas(16) unsigned short smem[16896];
  unsigned short* As = smem;
  unsigned short* Bs = smem + 4096;

  const int tid = threadIdx.x;
  const int m0 = blockIdx.y * 128, n0 = blockIdx.x * 128;
  const int w = tid >> 6, lane = tid & 63;
  const int wr = (w >> 1) * 64, wc = (w & 1) * 64;
  const int g = lane >> 4, r = lane & 15;

  f32x4 acc[4][4];
#pragma unroll
  for (int i = 0; i < 4; ++i)
#pragma unroll
    for (int j = 0; j < 4; ++j)
      acc[i][j] = f32x4{0.f, 0.f, 0.f, 0.f};

  const int srow = w * 32 + (lane >> 2);
  const int sk = (lane & 3) << 3;
  const size_t a_base = (size_t)(m0 + srow) * K + sk;
  const size_t b_base = (size_t)(n0 + srow) * K + sk;
  unsigned short* lA = &As[w * 1024 + lane * 8];
  unsigned short* lB = &Bs[w * 1024 + lane * 8];
  const size_t rstep = (size_t)16 * K;

  for (int k0 = 0; k0 < K; k0 += 32) {
    __syncthreads();
    gload_lds16(&A[a_base + k0], lA);
    gload_lds16(&A[a_base + k0 + rstep], lA + 512);
    gload_lds16(&BT[b_base + k0], lB);
    gload_lds16(&BT[b_base + k0 + rstep], lB + 512);
    __syncthreads();

    bf16x8 af[4], bff[4];
#pragma unroll
    for (int i = 0; i < 4; ++i)
      af[i] = __builtin_bit_cast(bf16x8,
          *reinterpret_cast<const uint4*>(&As[(wr + i * 16 + r) * 32 + g * 8]));
#pragma unroll
    for (int j = 0; j < 4; ++j)
      bff[j] = __builtin_bit_cast(bf16x8,
          *reinterpret_cast<const uint4*>(&Bs[(wc + j * 16 + r) * 32 + g * 8]));
#pragma unroll
    for (int i = 0; i < 4; ++i)
#pragma unroll
      for (int j = 0; j < 4; ++j)
        acc[i][j] = __builtin_amdgcn_mfma_f32_16x16x32_bf16(af[i], bff[j], acc[i][j], 0, 0, 0);
  }

  if constexpr (!C_IS_F32) {
    // ---- LDS-repack epilogue: [128][132] bf16 (pad 132 => g-rows hit
    //      disjoint bank octets), then coalesced row stores ----
    __syncthreads();           // K-loop LDS reads complete; reuse smem
    unsigned short* ct = smem;
#pragma unroll
    for (int i = 0; i < 4; ++i)
#pragma unroll
      for (int j = 0; j < 4; ++j) {
        int row0 = wr + i * 16 + g * 4;
        int col  = wc + j * 16 + r;
        unsigned int w01 = cvtpk(acc[i][j][0], acc[i][j][1]);
        unsigned int w23 = cvtpk(acc[i][j][2], acc[i][j][3]);
        ct[(row0 + 0) * 132 + col] = (unsigned short)(w01 & 0xffffu);
        ct[(row0 + 1) * 132 + col] = (unsigned short)(w01 >> 16);
        ct[(row0 + 2) * 132 + col] = (unsigned short)(w23 & 0xffffu);
        ct[(row0 + 3) * 132 + col] = (unsigned short)(w23 >> 16);
      }
    __syncthreads();
    unsigned short* C = (unsigned short*)Cp;
    const int prow = tid >> 4, pcol = (tid & 15) * 8;   // 16 lanes cover a 256B row
#pragma unroll
    for (int p = 0; p < 8; ++p) {
      int row = p * 16 + prow;
      uint4 v = *reinterpret_cast<const uint4*>(&ct[row * 132 + pcol]);
      *reinterpret_cast<uint4*>(&C[(size_t)(m0 + row) * N + n0 + pcol]) = v;
    }
  } else {
    // f32 output: direct stores (4B, 64B segments) — acceptable for gemm2
#pragma unroll
    for (int i = 0; i < 4; ++i)
#pragma unroll
      for (int j = 0; j < 4; ++j)
#pragma unroll
        for (int reg = 0; reg < 4; ++reg) {
          int row = m0 + wr + i * 16 + g * 4 + reg;
          int col = n0 + wc + j * 16 + r;
          ((float*)Cp)[(size_t)row * N + col] = acc[i][j][reg];
        }
  }
}

// ---------------------------------------------------------------------------
// RoPE + scatter: qkv bf16 (B,T,3D) -> Q,K (rope'd), V in (B,H,T,HD) bf16.
// ---------------------------------------------------------------------------
__global__ __launch_bounds__(256) void rope_scatter_kernel(
    const unsigned short* __restrict__ qkv, const float* __restrict__ rope,
    unsigned short* __restrict__ Qb, unsigned short* __restrict__ Kb,
    unsigned short* __restrict__ Vb)
{
  int gid = blockIdx.x * 256 + threadIdx.x;
  int rowM = gid / 768;
  int c4 = (gid - rowM * 768) * 4;
  int b = rowM >> 11, t = rowM & 2047;
  int sec = c4 >> 10;                         // 0=q 1=k 2=v
  int d = c4 & 1023;
  int h = d >> 6, hd = d & 63;

  uint2 vv = *reinterpret_cast<const uint2*>(&qkv[(size_t)rowM * 3072 + c4]);
  size_t dst = ((size_t)(b * 16 + h) * 2048 + t) * 64 + hd;

  if (sec == 2) {
    *reinterpret_cast<uint2*>(&Vb[dst]) = vv;
    return;
  }
  float x0 = bf2f((unsigned short)(vv.x & 0xffffu));
  float x1 = bf2f((unsigned short)(vv.x >> 16));
  float x2 = bf2f((unsigned short)(vv.y & 0xffffu));
  float x3 = bf2f((unsigned short)(vv.y >> 16));
  float4 rc = *reinterpret_cast<const float4*>(&rope[(size_t)t * 64 + hd]);
  float y0 = x0 * rc.x - x1 * rc.y;
  float y1 = x1 * rc.x + x0 * rc.y;
  float y2 = x2 * rc.z - x3 * rc.w;
  float y3 = x3 * rc.z + x2 * rc.w;
  uint2 outv;
  outv.x = pack2(y0, y1);
  outv.y = pack2(y2, y3);
  unsigned short* dstp = (sec == 0) ? Qb : Kb;
  *reinterpret_cast<uint2*>(&dstp[dst]) = outv;
}

// ---------------------------------------------------------------------------
// MFMA causal flash attention, 8 waves (512 thr), double-buffered staging,
// swapped-operand QK^T; per-lane scalar softmax; shuffle P-exchange;
// T13 defer-max; cvt_pk packing.
// Q/K bf16 (B,H,T,64); VT bf16 (B,H,64,T); O bf16 (B,T,D).
// ---------------------------------------------------------------------------
__global__ __launch_bounds__(512, 4) void attn_mfma_kernel(
    const unsigned short* __restrict__ Q, const unsigned short* __restrict__ K,
    const unsigned short* __restrict__ VT, unsigned short* __restrict__ O)
{
  __shared__ unsigned short Ks[2][64 * 64];  // [key][d] swizzled, dbuf
  __shared__ unsigned short Vs[2][64 * 64];  // [d][key] swizzled, dbuf

  const int bx = blockIdx.x;
  const int idx = bx & 255, hi = bx >> 8;
  const int bh = hi * 16 + (idx >> 4);
  const int tp = idx & 15;
  const int tile = hi ? tp : 15 - tp;        // complementary work pairing
  const int b = bh >> 4, h = bh & 15;
  const size_t base = (size_t)bh * 2048 * 64;
  const unsigned short* VTb = VT + (size_t)bh * 64 * 2048;

  const int tid = threadIdx.x, w = tid >> 6, lane = tid & 63;
  const int g = lane >> 4, r = lane & 15;
  const int q0 = tile * 128;
  const int wrow0 = q0 + w * 16;             // wave's 16 q-rows

  // Q as B-operand: col = q-row = wrow0+r, k = d = kk*32+g*8+j
  bf16x8 qf[2];
#pragma unroll
  for (int kk = 0; kk < 2; ++kk)
    qf[kk] = __builtin_bit_cast(bf16x8, *reinterpret_cast<const uint4*>(
        &Q[base + (size_t)(wrow0 + r) * 64 + kk * 32 + g * 8]));

  float m = -1e30f, l = 0.f;                 // per-lane scalar (q-row r)
  f32x4 ov[4];                               // O^T: row d = df*16+g*4+reg, col q=r
#pragma unroll
  for (int df = 0; df < 4; ++df) ov[df] = f32x4{0.f, 0.f, 0.f, 0.f};

  // staging: thread loads one uint4 of K and one of VT per tile
  const int srow = tid >> 3, sc8 = (tid & 7) * 8;
  const unsigned short* Kg = &K[base + (size_t)srow * 64 + sc8];
  const unsigned short* Vg = &VTb[(size_t)srow * 2048 + sc8];
  const int sb = srow * 128 + ((sc8 * 2) ^ ((srow & 7) << 4));

  const float cs = 0.125f * 1.44269504f;
  const int nkt = (q0 >> 6) + 2;

  // P-exchange sources (key-bit remap, verified algebraically)
  const int srcA = ((g & 1) << 5) | r;
  const int srcB = srcA | 16;
  const bool hsel = (g >> 1) != 0;

  // prologue: stage tile 0
  uint4 kreg = *reinterpret_cast<const uint4*>(Kg);
  uint4 vreg = *reinterpret_cast<const uint4*>(Vg);
  *reinterpret_cast<uint4*>((char*)Ks[0] + sb) = kreg;
  *reinterpret_cast<uint4*>((char*)Vs[0] + sb) = vreg;
  __syncthreads();

  for (int c = 0; c < nkt; ++c) {
    const int kb = c * 64;
    const int cur = c & 1;
    const bool pfn = (c + 1 < nkt);
    if (pfn) {   // issue next-tile loads early (latency hides under compute)
      kreg = *reinterpret_cast<const uint4*>(Kg + (size_t)(kb + 64) * 64);
      vreg = *reinterpret_cast<const uint4*>(Vg + kb + 64);
    }

    if (kb <= wrow0 + 15) {
      // --- QK^T swapped: lane holds S[key=kb+cf*16+g*4+reg][q=wrow0+r]
      f32x4 s[4];
#pragma unroll
      for (int cf = 0; cf < 4; ++cf) s[cf] = f32x4{0.f, 0.f, 0.f, 0.f};
      __builtin_amdgcn_s_setprio(1);
#pragma unroll
      for (int kk = 0; kk < 2; ++kk) {
#pragma unroll
        for (int cf = 0; cf < 4; ++cf) {
          int row = cf * 16 + r;
          const char* p = (const char*)Ks[cur] + row * 128 + ((kk * 64 + g * 16) ^ ((r & 7) << 4));
          bf16x8 kf = __builtin_bit_cast(bf16x8, *reinterpret_cast<const uint4*>(p));
          s[cf] = __builtin_amdgcn_mfma_f32_16x16x32_bf16(kf, qf[kk], s[cf], 0, 0, 0);
        }
      }
      __builtin_amdgcn_s_setprio(0);

      // --- causal mask (diagonal region only): key > q-row -> -inf
      if (kb + 63 > wrow0) {
#pragma unroll
        for (int cf = 0; cf < 4; ++cf) {
          int keyb = kb + cf * 16 + g * 4;
#pragma unroll
          for (int reg = 0; reg < 4; ++reg)
            if (keyb + reg > wrow0 + r) s[cf][reg] = -1e30f;
        }
      }

      // --- online softmax with T13 defer-max ---
      float vmx = s[0][0];
#pragma unroll
      for (int cf = 0; cf < 4; ++cf)
#pragma unroll
        for (int reg = 0; reg < 4; ++reg)
          vmx = fmaxf(vmx, s[cf][reg]);
      vmx = fmaxf(vmx, __shfl_xor(vmx, 16));
      vmx = fmaxf(vmx, __shfl_xor(vmx, 32));
      float mo = m;
      float mn, al;
      if (__all((vmx - mo) * cs <= 4.0f)) {   // bounded growth: skip rescale
        mn = mo; al = 1.0f;
      } else {
        mn = fmaxf(mo, vmx);
        al = __builtin_amdgcn_exp2f((mo - mn) * cs);
        m = mn;
#pragma unroll
        for (int df = 0; df < 4; ++df) ov[df] *= al;
      }
      float ps = 0.f;
#pragma unroll
      for (int cf = 0; cf < 4; ++cf)
#pragma unroll
        for (int reg = 0; reg < 4; ++reg) {
          float p = __builtin_amdgcn_exp2f((s[cf][reg] - mn) * cs);
          s[cf][reg] = p;
          ps += p;
        }
      l = l * al + ps;

      // pack P to bf16 pairs (hardware cvt_pk)
      unsigned int pk[4][2];
#pragma unroll
      for (int cf = 0; cf < 4; ++cf) {
        pk[cf][0] = cvtpk(s[cf][0], s[cf][1]);
        pk[cf][1] = cvtpk(s[cf][2], s[cf][3]);
      }

      // --- exchange P into B-operand fragments + PV ---
      __builtin_amdgcn_s_setprio(1);
#pragma unroll
      for (int kk = 0; kk < 2; ++kk) {
        unsigned int a0 = __shfl(pk[2 * kk][0], srcA), b0 = __shfl(pk[2 * kk + 1][0], srcA);
        unsigned int a1 = __shfl(pk[2 * kk][1], srcA), b1 = __shfl(pk[2 * kk + 1][1], srcA);
        unsigned int a2 = __shfl(pk[2 * kk][0], srcB), b2 = __shfl(pk[2 * kk + 1][0], srcB);
        unsigned int a3 = __shfl(pk[2 * kk][1], srcB), b3 = __shfl(pk[2 * kk + 1][1], srcB);
        uint4 pw{ hsel ? b0 : a0, hsel ? b1 : a1, hsel ? b2 : a2, hsel ? b3 : a3 };
        bf16x8 pf = __builtin_bit_cast(bf16x8, pw);
#pragma unroll
        for (int df = 0; df < 4; ++df) {
          int row = df * 16 + r;
          const char* p = (const char*)Vs[cur] + row * 128 + ((kk * 64 + g * 16) ^ ((r & 7) << 4));
          bf16x8 vf = __builtin_bit_cast(bf16x8, *reinterpret_cast<const uint4*>(p));
          ov[df] = __builtin_amdgcn_mfma_f32_16x16x32_bf16(vf, pf, ov[df], 0, 0, 0);
        }
      }
      __builtin_amdgcn_s_setprio(0);
    }

    if (pfn) {   // write next tile into the other buffer
      *reinterpret_cast<uint4*>((char*)Ks[cur ^ 1] + sb) = kreg;
      *reinterpret_cast<uint4*>((char*)Vs[cur ^ 1] + sb) = vreg;
    }
    __syncthreads();
  }

  // --- finalize: l summed across the 4 g-lanes of this q-row ---
  float ls = l;
  ls += __shfl_xor(ls, 16);
  ls += __shfl_xor(ls, 32);
  float inv = 1.f / ls;
  size_t orow = (size_t)(b * 2048 + wrow0 + r) * 1024 + h * 64 + g * 4;
#pragma unroll
  for (int df = 0; df < 4; ++df) {
    uint2 o;
    o.x = cvtpk(ov[df][0] * inv, ov[df][1] * inv);
    o.y = cvtpk(ov[df][2] * inv, ov[df][3] * inv);
    *reinterpret_cast<uint2*>(&O[orow + df * 16]) = o;
  }
}

// ---------------------------------------------------------------------------
extern "C" void kernel_launch(void* const* d_in, const int* in_sizes, int n_in,
                              void* d_out, int out_size, void* d_ws, size_t ws_size,
                              hipStream_t stream)
{
  (void)in_sizes; (void)n_in; (void)out_size; (void)ws_size;
  const float* x    = (const float*)d_in[0];   // (B,T,D) f32
  const float* rope = (const float*)d_in[1];   // (T,32,2) f32
  const float* Wa   = (const float*)d_in[2];   // (D,3D) f32
  const float* Wp   = (const float*)d_in[3];   // (D,D) f32
  // d_in[4] = causal mask (ignored; recomputed)

  unsigned short* ws  = (unsigned short*)d_ws;
  unsigned short* qkv = ws;                                // 12.58M elems
  unsigned short* Qb  = qkv + (size_t)4096 * 3072;
  unsigned short* Kb  = Qb + (size_t)32 * 2048 * 64;
  unsigned short* Vb  = Kb + (size_t)32 * 2048 * 64;
  unsigned short* WpT = Vb + (size_t)32 * 2048 * 64;
  unsigned short* xb  = Qb;                      // alias: dead before rope writes Qb
  unsigned short* WaT = Kb;                      // alias: dead before rope writes Kb
  unsigned short* O   = qkv;                     // alias: qkv dead after rope
  unsigned short* VT  = qkv + (size_t)4096 * 1024;  // alias: disjoint from O region
  float* out = (float*)d_out;

  prep_kernel<<<3072, 256, 0, stream>>>(x, xb, Wa, WaT, Wp, WpT);
  gemm_bt_kernel<false><<<dim3(3072 / 128, 4096 / 128), 256, 0, stream>>>(
      xb, WaT, qkv, 4096, 3072, 1024);
  rope_scatter_kernel<<<(4096 * 3072 / 4) / 256, 256, 0, stream>>>(qkv, rope, Qb, Kb, Vb);
  transpose_v_kernel<<<dim3(32, 32), 256, 0, stream>>>(Vb, VT);
  attn_mfma_kernel<<<512, 512, 0, stream>>>(Qb, Kb, VT, O);
  gemm_bt_kernel<true><<<dim3(1024 / 128, 4096 / 128), 256, 0, stream>>>(
      O, WpT, out, 4096, 1024, 1024);
}

// Round 10
// 199.981 us; speedup vs baseline: 6.7476x; 1.1129x over previous
//
#include <hip/hip_runtime.h>

// B=2, T=2048, D=1024, H=16, HD=64.
// Inputs f32 (x, rope, W_attn, W_proj), mask ignored (causal recomputed).
// Output f32. Internal tensors bf16 in workspace.
// Pipeline: prep -> gemm_qkv (fused rope/scatter/V-transpose) -> attn -> gemm2.

typedef __bf16 bf16x8 __attribute__((ext_vector_type(8)));
typedef float f32x4 __attribute__((ext_vector_type(4)));

__device__ __forceinline__ float bf2f(unsigned short u) {
  unsigned int i = ((unsigned int)u) << 16;
  return __builtin_bit_cast(float, i);
}
__device__ __forceinline__ unsigned short f2bf(float f) {
  unsigned int i = __builtin_bit_cast(unsigned int, f);
  i += 0x7FFFu + ((i >> 16) & 1u);   // round-to-nearest-even
  return (unsigned short)(i >> 16);
}
__device__ __forceinline__ unsigned int pack2(float a, float b) {
  return (unsigned int)f2bf(a) | ((unsigned int)f2bf(b) << 16);
}
// hardware packed f32->bf16 (RNE), lo = a, hi = b
__device__ __forceinline__ unsigned int cvtpk(float a, float b) {
  unsigned int r;
  asm("v_cvt_pk_bf16_f32 %0, %1, %2" : "=v"(r) : "v"(a), "v"(b));
  return r;
}

// async global->LDS, 16B per lane (lds dest = wave base + lane*16)
__device__ __forceinline__ void gload_lds16(const unsigned short* g, unsigned short* l) {
  __builtin_amdgcn_global_load_lds(
      (const __attribute__((address_space(1))) void*)g,
      (__attribute__((address_space(3))) void*)l, 16, 0, 0);
}

// ---------------------------------------------------------------------------
// Fused prep: [0,2048) convert x ; [2048,2816) transpose Wa ; [2816,3072) Wp.
// ---------------------------------------------------------------------------
__global__ __launch_bounds__(256) void prep_kernel(
    const float* __restrict__ x, unsigned short* __restrict__ xb,
    const float* __restrict__ Wa, unsigned short* __restrict__ WaT,
    const float* __restrict__ Wp, unsigned short* __restrict__ WpT)
{
  __shared__ unsigned short tileT[64][72];   // [c][r], padded
  const int bid = blockIdx.x, tid = threadIdx.x;

  if (bid < 2048) {             // ---- convert x (8 elems/thread) ----
    int i = bid * 256 + tid;
    const float4 a0 = *reinterpret_cast<const float4*>(&x[(size_t)i * 8]);
    const float4 a1 = *reinterpret_cast<const float4*>(&x[(size_t)i * 8 + 4]);
    uint4 pk;
    pk.x = pack2(a0.x, a0.y);
    pk.y = pack2(a0.z, a0.w);
    pk.z = pack2(a1.x, a1.y);
    pk.w = pack2(a1.z, a1.w);
    *reinterpret_cast<uint4*>(&xb[(size_t)i * 8]) = pk;
    return;
  }
  const float* W;
  unsigned short* WT;
  int R, C, c0, r0;
  if (bid < 2816) {
    int tb = bid - 2048;        // Wa: 48 x 16 tiles
    W = Wa; WT = WaT; R = 1024; C = 3072;
    c0 = (tb % 48) * 64; r0 = (tb / 48) * 64;
  } else {
    int tb = bid - 2816;        // Wp: 16 x 16 tiles
    W = Wp; WT = WpT; R = 1024; C = 1024;
    c0 = (tb % 16) * 64; r0 = (tb / 16) * 64;
  }
  const int rr = tid >> 4, cc = (tid & 15) * 4;
#pragma unroll
  for (int it = 0; it < 4; ++it) {
    int gr = r0 + rr + it * 16;
    float4 v = *reinterpret_cast<const float4*>(&W[(size_t)gr * C + c0 + cc]);
    tileT[cc + 0][rr + it * 16] = f2bf(v.x);
    tileT[cc + 1][rr + it * 16] = f2bf(v.y);
    tileT[cc + 2][rr + it * 16] = f2bf(v.z);
    tileT[cc + 3][rr + it * 16] = f2bf(v.w);
  }
  __syncthreads();
  const int wc = tid >> 2, wk = (tid & 3) * 16;
  uint4 o0 = *reinterpret_cast<const uint4*>(&tileT[wc][wk]);
  uint4 o1 = *reinterpret_cast<const uint4*>(&tileT[wc][wk + 8]);
  unsigned short* dst = &WT[(size_t)(c0 + wc) * R + r0 + wk];
  *reinterpret_cast<uint4*>(dst) = o0;
  *reinterpret_cast<uint4*>(dst + 8) = o1;
}

// ---------------------------------------------------------------------------
// Fused QKV GEMM: qkv_tile = xb * WaT^T, then per-block (section-uniform):
//   sec 0/1 (q/k): rope applied in-epilogue, scatter to Qb/Kb (B,H,T,64)
//   sec 2   (v)  : transposed write to VT (B,H,64,T)
// 128x128 tile, BK=32, 4 waves, m97 K-loop. XCD-swizzled block mapping.
// ---------------------------------------------------------------------------
__global__ __launch_bounds__(256) void gemm_qkv_kernel(
    const unsigned short* __restrict__ A, const unsigned short* __restrict__ BT,
    const float* __restrict__ rope,
    unsigned short* __restrict__ Qb, unsigned short* __restrict__ Kb,
    unsigned short* __restrict__ VT, int M, int N, int K)
{
  __shared__ alignas(16) unsigned short smem[16896];
  unsigned short* As = smem;
  unsigned short* Bs = smem + 4096;

  const int tid = threadIdx.x;
  // XCD-aware swizzle (bijective: nwg % 8 == 0)
  const int nbx = gridDim.x;
  const int nwg = nbx * gridDim.y;
  const int orig = blockIdx.y * nbx + blockIdx.x;
  const int wg = (orig & 7) * (nwg >> 3) + (orig >> 3);
  const int m0 = (wg / nbx) * 128, n0 = (wg % nbx) * 128;

  const int w = tid >> 6, lane = tid & 63;
  const int wr = (w >> 1) * 64, wc = (w & 1) * 64;
  const int g = lane >> 4, r = lane & 15;

  f32x4 acc[4][4];
#pragma unroll
  for (int i = 0; i < 4; ++i)
#pragma unroll
    for (int j = 0; j < 4; ++j)
      acc[i][j] = f32x4{0.f, 0.f, 0.f, 0.f};

  const int srow = w * 32 + (lane >> 2);
  const int sk = (lane & 3) << 3;
  const size_t a_base = (size_t)(m0 + srow) * K + sk;
  const size_t b_base = (size_t)(n0 + srow) * K + sk;
  unsigned short* lA = &As[w * 1024 + lane * 8];
  unsigned short* lB = &Bs[w * 1024 + lane * 8];
  const size_t rstep = (size_t)16 * K;

  for (int k0 = 0; k0 < K; k0 += 32) {
    __syncthreads();
    gload_lds16(&A[a_base + k0], lA);
    gload_lds16(&A[a_base + k0 + rstep], lA + 512);
    gload_lds16(&BT[b_base + k0], lB);
    gload_lds16(&BT[b_base + k0 + rstep], lB + 512);
    __syncthreads();

    bf16x8 af[4], bff[4];
#pragma unroll
    for (int i = 0; i < 4; ++i)
      af[i] = __builtin_bit_cast(bf16x8,
          *reinterpret_cast<const uint4*>(&As[(wr + i * 16 + r) * 32 + g * 8]));
#pragma unroll
    for (int j = 0; j < 4; ++j)
      bff[j] = __builtin_bit_cast(bf16x8,
          *reinterpret_cast<const uint4*>(&Bs[(wc + j * 16 + r) * 32 + g * 8]));
#pragma unroll
    for (int i = 0; i < 4; ++i)
#pragma unroll
      for (int j = 0; j < 4; ++j)
        acc[i][j] = __builtin_amdgcn_mfma_f32_16x16x32_bf16(af[i], bff[j], acc[i][j], 0, 0, 0);
  }

  // ---- bf16 LDS repack: ct[128][132] ----
  __syncthreads();
  unsigned short* ct = smem;
#pragma unroll
  for (int i = 0; i < 4; ++i)
#pragma unroll
    for (int j = 0; j < 4; ++j) {
      int row0 = wr + i * 16 + g * 4;
      int col  = wc + j * 16 + r;
      unsigned int w01 = cvtpk(acc[i][j][0], acc[i][j][1]);
      unsigned int w23 = cvtpk(acc[i][j][2], acc[i][j][3]);
      ct[(row0 + 0) * 132 + col] = (unsigned short)(w01 & 0xffffu);
      ct[(row0 + 1) * 132 + col] = (unsigned short)(w01 >> 16);
      ct[(row0 + 2) * 132 + col] = (unsigned short)(w23 & 0xffffu);
      ct[(row0 + 3) * 132 + col] = (unsigned short)(w23 >> 16);
    }
  __syncthreads();

  const int sec = n0 >> 10;     // 0=q 1=k 2=v (tile never spans sections)
  if (sec < 2) {
    // ---- rope + scatter to (B,H,T,64) ----
    unsigned short* dstp = (sec == 0) ? Qb : Kb;
    const int prow = tid >> 4, pcol = (tid & 15) * 8;
    const int h = ((n0 & 1023) + pcol) >> 6;
    const int hd = pcol & 63;
#pragma unroll
    for (int p = 0; p < 8; ++p) {
      int row = p * 16 + prow;
      int rowM = m0 + row;
      int bb = rowM >> 11, tt = rowM & 2047;
      uint4 v = *reinterpret_cast<const uint4*>(&ct[row * 132 + pcol]);
      float x0 = bf2f((unsigned short)(v.x & 0xffffu)), x1 = bf2f((unsigned short)(v.x >> 16));
      float x2 = bf2f((unsigned short)(v.y & 0xffffu)), x3 = bf2f((unsigned short)(v.y >> 16));
      float x4 = bf2f((unsigned short)(v.z & 0xffffu)), x5 = bf2f((unsigned short)(v.z >> 16));
      float x6 = bf2f((unsigned short)(v.w & 0xffffu)), x7 = bf2f((unsigned short)(v.w >> 16));
      float4 rc0 = *reinterpret_cast<const float4*>(&rope[(size_t)tt * 64 + hd]);
      float4 rc1 = *reinterpret_cast<const float4*>(&rope[(size_t)tt * 64 + hd + 4]);
      float y0 = x0 * rc0.x - x1 * rc0.y, y1 = x1 * rc0.x + x0 * rc0.y;
      float y2 = x2 * rc0.z - x3 * rc0.w, y3 = x3 * rc0.z + x2 * rc0.w;
      float y4 = x4 * rc1.x - x5 * rc1.y, y5 = x5 * rc1.x + x4 * rc1.y;
      float y6 = x6 * rc1.z - x7 * rc1.w, y7 = x7 * rc1.z + x6 * rc1.w;
      uint4 o{cvtpk(y0, y1), cvtpk(y2, y3), cvtpk(y4, y5), cvtpk(y6, y7)};
      *reinterpret_cast<uint4*>(&dstp[((size_t)(bb * 16 + h) * 2048 + tt) * 64 + hd]) = o;
    }
  } else {
    // ---- transposed write to VT (B,H,64,T) ----
    const int col = tid >> 1, tch = (tid & 1) * 64;
    const int h = ((n0 - 2048) >> 6) + (col >> 6);
    const int hd = col & 63;
    const int bb = m0 >> 11, tt0 = m0 & 2047;
    unsigned short* vdst = &VT[((size_t)(bb * 16 + h) * 64 + hd) * 2048 + tt0 + tch];
#pragma unroll
    for (int j = 0; j < 8; ++j) {
      int t = tch + j * 8;
      unsigned int o0 = (unsigned int)ct[(t + 0) * 132 + col] | ((unsigned int)ct[(t + 1) * 132 + col] << 16);
      unsigned int o1 = (unsigned int)ct[(t + 2) * 132 + col] | ((unsigned int)ct[(t + 3) * 132 + col] << 16);
      unsigned int o2 = (unsigned int)ct[(t + 4) * 132 + col] | ((unsigned int)ct[(t + 5) * 132 + col] << 16);
      unsigned int o3 = (unsigned int)ct[(t + 6) * 132 + col] | ((unsigned int)ct[(t + 7) * 132 + col] << 16);
      *reinterpret_cast<uint4*>(&vdst[j * 8]) = uint4{o0, o1, o2, o3};
    }
  }
}

// ---------------------------------------------------------------------------
// Output GEMM: out(MxN f32) = A(MxK bf16) * BT(NxK bf16)^T. m97 K-loop.
// ---------------------------------------------------------------------------
__global__ __launch_bounds__(256) void gemm_out_kernel(
    const unsigned short* __restrict__ A, const unsigned short* __restrict__ BT,
    float* __restrict__ Cp, int M, int N, int K)
{
  __shared__ alignas(16) unsigned short As[128 * 32];
  __shared__ alignas(16) unsigned short Bs[128 * 32];

  const int tid = threadIdx.x;
  const int nbx = gridDim.x;
  const int nwg = nbx * gridDim.y;
  const int orig = blockIdx.y * nbx + blockIdx.x;
  const int wg = (orig & 7) * (nwg >> 3) + (orig >> 3);
  const int m0 = (wg / nbx) * 128, n0 = (wg % nbx) * 128;

  const int w = tid >> 6, lane = tid & 63;
  const int wr = (w >> 1) * 64, wc = (w & 1) * 64;
  const int g = lane >> 4, r = lane & 15;

  f32x4 acc[4][4];
#pragma unroll
  for (int i = 0; i < 4; ++i)
#pragma unroll
    for (int j = 0; j < 4; ++j)
      acc[i][j] = f32x4{0.f, 0.f, 0.f, 0.f};

  const int srow = w * 32 + (lane >> 2);
  const int sk = (lane & 3) << 3;
  const size_t a_base = (size_t)(m0 + srow) * K + sk;
  const size_t b_base = (size_t)(n0 + srow) * K + sk;
  unsigned short* lA = &As[w * 1024 + lane * 8];
  unsigned short* lB = &Bs[w * 1024 + lane * 8];
  const size_t rstep = (size_t)16 * K;

  for (int k0 = 0; k0 < K; k0 += 32) {
    __syncthreads();
    gload_lds16(&A[a_base + k0], lA);
    gload_lds16(&A[a_base + k0 + rstep], lA + 512);
    gload_lds16(&BT[b_base + k0], lB);
    gload_lds16(&BT[b_base + k0 + rstep], lB + 512);
    __syncthreads();

    bf16x8 af[4], bff[4];
#pragma unroll
    for (int i = 0; i < 4; ++i)
      af[i] = __builtin_bit_cast(bf16x8,
          *reinterpret_cast<const uint4*>(&As[(wr + i * 16 + r) * 32 + g * 8]));
#pragma unroll
    for (int j = 0; j < 4; ++j)
      bff[j] = __builtin_bit_cast(bf16x8,
          *reinterpret_cast<const uint4*>(&Bs[(wc + j * 16 + r) * 32 + g * 8]));
#pragma unroll
    for (int i = 0; i < 4; ++i)
#pragma unroll
      for (int j = 0; j < 4; ++j)
        acc[i][j] = __builtin_amdgcn_mfma_f32_16x16x32_bf16(af[i], bff[j], acc[i][j], 0, 0, 0);
  }

#pragma unroll
  for (int i = 0; i < 4; ++i)
#pragma unroll
    for (int j = 0; j < 4; ++j)
#pragma unroll
      for (int reg = 0; reg < 4; ++reg) {
        int row = m0 + wr + i * 16 + g * 4 + reg;
        int col = n0 + wc + j * 16 + r;
        Cp[(size_t)row * N + col] = acc[i][j][reg];
      }
}

// ---------------------------------------------------------------------------
// MFMA causal flash attention (unchanged from round 9).
// ---------------------------------------------------------------------------
__global__ __launch_bounds__(512, 4) void attn_mfma_kernel(
    const unsigned short* __restrict__ Q, const unsigned short* __restrict__ K,
    const unsigned short* __restrict__ VT, unsigned short* __restrict__ O)
{
  __shared__ unsigned short Ks[2][64 * 64];  // [key][d] swizzled, dbuf
  __shared__ unsigned short Vs[2][64 * 64];  // [d][key] swizzled, dbuf

  const int bx = blockIdx.x;
  const int idx = bx & 255, hi = bx >> 8;
  const int bh = hi * 16 + (idx >> 4);
  const int tp = idx & 15;
  const int tile = hi ? tp : 15 - tp;        // complementary work pairing
  const int b = bh >> 4, h = bh & 15;
  const size_t base = (size_t)bh * 2048 * 64;
  const unsigned short* VTb = VT + (size_t)bh * 64 * 2048;

  const int tid = threadIdx.x, w = tid >> 6, lane = tid & 63;
  const int g = lane >> 4, r = lane & 15;
  const int q0 = tile * 128;
  const int wrow0 = q0 + w * 16;             // wave's 16 q-rows

  bf16x8 qf[2];
#pragma unroll
  for (int kk = 0; kk < 2; ++kk)
    qf[kk] = __builtin_bit_cast(bf16x8, *reinterpret_cast<const uint4*>(
        &Q[base + (size_t)(wrow0 + r) * 64 + kk * 32 + g * 8]));

  float m = -1e30f, l = 0.f;                 // per-lane scalar (q-row r)
  f32x4 ov[4];
#pragma unroll
  for (int df = 0; df < 4; ++df) ov[df] = f32x4{0.f, 0.f, 0.f, 0.f};

  const int srow = tid >> 3, sc8 = (tid & 7) * 8;
  const unsigned short* Kg = &K[base + (size_t)srow * 64 + sc8];
  const unsigned short* Vg = &VTb[(size_t)srow * 2048 + sc8];
  const int sb = srow * 128 + ((sc8 * 2) ^ ((srow & 7) << 4));

  const float cs = 0.125f * 1.44269504f;
  const int nkt = (q0 >> 6) + 2;

  const int srcA = ((g & 1) << 5) | r;
  const int srcB = srcA | 16;
  const bool hsel = (g >> 1) != 0;

  uint4 kreg = *reinterpret_cast<const uint4*>(Kg);
  uint4 vreg = *reinterpret_cast<const uint4*>(Vg);
  *reinterpret_cast<uint4*>((char*)Ks[0] + sb) = kreg;
  *reinterpret_cast<uint4*>((char*)Vs[0] + sb) = vreg;
  __syncthreads();

  for (int c = 0; c < nkt; ++c) {
    const int kb = c * 64;
    const int cur = c & 1;
    const bool pfn = (c + 1 < nkt);
    if (pfn) {
      kreg = *reinterpret_cast<const uint4*>(Kg + (size_t)(kb + 64) * 64);
      vreg = *reinterpret_cast<const uint4*>(Vg + kb + 64);
    }

    if (kb <= wrow0 + 15) {
      f32x4 s[4];
#pragma unroll
      for (int cf = 0; cf < 4; ++cf) s[cf] = f32x4{0.f, 0.f, 0.f, 0.f};
      __builtin_amdgcn_s_setprio(1);
#pragma unroll
      for (int kk = 0; kk < 2; ++kk) {
#pragma unroll
        for (int cf = 0; cf < 4; ++cf) {
          int row = cf * 16 + r;
          const char* p = (const char*)Ks[cur] + row * 128 + ((kk * 64 + g * 16) ^ ((r & 7) << 4));
          bf16x8 kf = __builtin_bit_cast(bf16x8, *reinterpret_cast<const uint4*>(p));
          s[cf] = __builtin_amdgcn_mfma_f32_16x16x32_bf16(kf, qf[kk], s[cf], 0, 0, 0);
        }
      }
      __builtin_amdgcn_s_setprio(0);

      if (kb + 63 > wrow0) {
#pragma unroll
        for (int cf = 0; cf < 4; ++cf) {
          int keyb = kb + cf * 16 + g * 4;
#pragma unroll
          for (int reg = 0; reg < 4; ++reg)
            if (keyb + reg > wrow0 + r) s[cf][reg] = -1e30f;
        }
      }

      float vmx = s[0][0];
#pragma unroll
      for (int cf = 0; cf < 4; ++cf)
#pragma unroll
        for (int reg = 0; reg < 4; ++reg)
          vmx = fmaxf(vmx, s[cf][reg]);
      vmx = fmaxf(vmx, __shfl_xor(vmx, 16));
      vmx = fmaxf(vmx, __shfl_xor(vmx, 32));
      float mo = m;
      float mn, al;
      if (__all((vmx - mo) * cs <= 4.0f)) {   // T13 defer-max
        mn = mo; al = 1.0f;
      } else {
        mn = fmaxf(mo, vmx);
        al = __builtin_amdgcn_exp2f((mo - mn) * cs);
        m = mn;
#pragma unroll
        for (int df = 0; df < 4; ++df) ov[df] *= al;
      }
      float ps = 0.f;
#pragma unroll
      for (int cf = 0; cf < 4; ++cf)
#pragma unroll
        for (int reg = 0; reg < 4; ++reg) {
          float p = __builtin_amdgcn_exp2f((s[cf][reg] - mn) * cs);
          s[cf][reg] = p;
          ps += p;
        }
      l = l * al + ps;

      unsigned int pk[4][2];
#pragma unroll
      for (int cf = 0; cf < 4; ++cf) {
        pk[cf][0] = cvtpk(s[cf][0], s[cf][1]);
        pk[cf][1] = cvtpk(s[cf][2], s[cf][3]);
      }

      __builtin_amdgcn_s_setprio(1);
#pragma unroll
      for (int kk = 0; kk < 2; ++kk) {
        unsigned int a0 = __shfl(pk[2 * kk][0], srcA), b0 = __shfl(pk[2 * kk + 1][0], srcA);
        unsigned int a1 = __shfl(pk[2 * kk][1], srcA), b1 = __shfl(pk[2 * kk + 1][1], srcA);
        unsigned int a2 = __shfl(pk[2 * kk][0], srcB), b2 = __shfl(pk[2 * kk + 1][0], srcB);
        unsigned int a3 = __shfl(pk[2 * kk][1], srcB), b3 = __shfl(pk[2 * kk + 1][1], srcB);
        uint4 pw{ hsel ? b0 : a0, hsel ? b1 : a1, hsel ? b2 : a2, hsel ? b3 : a3 };
        bf16x8 pf = __builtin_bit_cast(bf16x8, pw);
#pragma unroll
        for (int df = 0; df < 4; ++df) {
          int row = df * 16 + r;
          const char* p = (const char*)Vs[cur] + row * 128 + ((kk * 64 + g * 16) ^ ((r & 7) << 4));
          bf16x8 vf = __builtin_bit_cast(bf16x8, *reinterpret_cast<const uint4*>(p));
          ov[df] = __builtin_amdgcn_mfma_f32_16x16x32_bf16(vf, pf, ov[df], 0, 0, 0);
        }
      }
      __builtin_amdgcn_s_setprio(0);
    }

    if (pfn) {
      *reinterpret_cast<uint4*>((char*)Ks[cur ^ 1] + sb) = kreg;
      *reinterpret_cast<uint4*>((char*)Vs[cur ^ 1] + sb) = vreg;
    }
    __syncthreads();
  }

  float ls = l;
  ls += __shfl_xor(ls, 16);
  ls += __shfl_xor(ls, 32);
  float inv = 1.f / ls;
  size_t orow = (size_t)(b * 2048 + wrow0 + r) * 1024 + h * 64 + g * 4;
#pragma unroll
  for (int df = 0; df < 4; ++df) {
    uint2 o;
    o.x = cvtpk(ov[df][0] * inv, ov[df][1] * inv);
    o.y = cvtpk(ov[df][2] * inv, ov[df][3] * inv);
    *reinterpret_cast<uint2*>(&O[orow + df * 16]) = o;
  }
}

// ---------------------------------------------------------------------------
extern "C" void kernel_launch(void* const* d_in, const int* in_sizes, int n_in,
                              void* d_out, int out_size, void* d_ws, size_t ws_size,
                              hipStream_t stream)
{
  (void)in_sizes; (void)n_in; (void)out_size; (void)ws_size;
  const float* x    = (const float*)d_in[0];   // (B,T,D) f32
  const float* rope = (const float*)d_in[1];   // (T,32,2) f32
  const float* Wa   = (const float*)d_in[2];   // (D,3D) f32
  const float* Wp   = (const float*)d_in[3];   // (D,D) f32
  // d_in[4] = causal mask (ignored; recomputed)

  // de-aliased workspace (elems): xb 4.19M | WaT 3.15M | WpT 1.05M |
  // Qb 4.19M | Kb 4.19M | VT 4.19M | O 4.19M  = 25.2M elems = 50.3 MB
  unsigned short* ws  = (unsigned short*)d_ws;
  unsigned short* xb  = ws;
  unsigned short* WaT = xb  + (size_t)4096 * 1024;
  unsigned short* WpT = WaT + (size_t)1024 * 3072;
  unsigned short* Qb  = WpT + (size_t)1024 * 1024;
  unsigned short* Kb  = Qb  + (size_t)32 * 2048 * 64;
  unsigned short* VT  = Kb  + (size_t)32 * 2048 * 64;
  unsigned short* O   = VT  + (size_t)32 * 2048 * 64;
  float* out = (float*)d_out;

  prep_kernel<<<3072, 256, 0, stream>>>(x, xb, Wa, WaT, Wp, WpT);
  gemm_qkv_kernel<<<dim3(3072 / 128, 4096 / 128), 256, 0, stream>>>(
      xb, WaT, rope, Qb, Kb, VT, 4096, 3072, 1024);
  attn_mfma_kernel<<<512, 512, 0, stream>>>(Qb, Kb, VT, O);
  gemm_out_kernel<<<dim3(1024 / 128, 4096 / 128), 256, 0, stream>>>(
      O, WpT, out, 4096, 1024, 1024);
}